// Round 1
// baseline (305.467 us; speedup 1.0000x reference)
//
#include <hip/hip_runtime.h>
#include <hip/hip_bf16.h>

// Problem dims
#define Bsz 128
#define Cch 256
#define Him 32
#define Wim 32
#define TD 192
#define NH 4
#define HD 48
#define FF 384
#define NP 64   // 8x8 patches
#define NTOK (Bsz*NP)   // 8192 token rows

// ---------------- patch mean: xm[b,p,c] = mean_{4x4} x[b,c,...] ----------------
__global__ __launch_bounds__(256) void patchmean_kernel(const float* __restrict__ x,
                                                        float* __restrict__ xm) {
    int g = blockIdx.x * 256 + threadIdx.x;        // B*C*64 = 2,097,152
    int nw = g & 7, nh = (g >> 3) & 7, c = (g >> 6) & 255, b = g >> 14;
    const float* px = x + ((size_t)(b * Cch + c) * Him + nh * 4) * Wim + nw * 4;
    float4 s0 = *reinterpret_cast<const float4*>(px);
    float4 s1 = *reinterpret_cast<const float4*>(px + Wim);
    float4 s2 = *reinterpret_cast<const float4*>(px + 2 * Wim);
    float4 s3 = *reinterpret_cast<const float4*>(px + 3 * Wim);
    float s = s0.x + s0.y + s0.z + s0.w + s1.x + s1.y + s1.z + s1.w +
              s2.x + s2.y + s2.z + s2.w + s3.x + s3.y + s3.z + s3.w;
    xm[(size_t)(b * NP + nh * 8 + nw) * Cch + c] = s * 0.0625f;
}

// ---------------- LayerNorm over TD=192, one 64-thread wave per row ----------------
__global__ __launch_bounds__(64) void ln_kernel(const float* __restrict__ in,
                                                const float* __restrict__ g,
                                                const float* __restrict__ bta,
                                                float* __restrict__ out) {
    int r = blockIdx.x, t = threadIdx.x;
    const float* row = in + (size_t)r * TD;
    float v0 = row[t], v1 = row[t + 64], v2 = row[t + 128];
    float s = v0 + v1 + v2;
    float s2 = v0 * v0 + v1 * v1 + v2 * v2;
    for (int o = 32; o; o >>= 1) { s += __shfl_down(s, o); s2 += __shfl_down(s2, o); }
    s = __shfl(s, 0); s2 = __shfl(s2, 0);
    float mean = s * (1.0f / TD);
    float var = s2 * (1.0f / TD) - mean * mean;
    float inv = rsqrtf(var + 1e-5f);
    float* orow = out + (size_t)r * TD;
    orow[t]       = (v0 - mean) * inv * g[t]       + bta[t];
    orow[t + 64]  = (v1 - mean) * inv * g[t + 64]  + bta[t + 64];
    orow[t + 128] = (v2 - mean) * inv * g[t + 128] + bta[t + 128];
}

// ---------------- generic tiled f32 GEMM, 64x64 tile, BK=16, fused epilogues ----------------
// EPI: 0 = C=acc ; 1 = +bias ; 2 = resid + alpha*(acc+bias) ; 3 = gelu(acc+bias) ; 4 = resid+acc+bias
template <bool BT, int EPI>
__global__ __launch_bounds__(256) void gemm_kernel(const float* __restrict__ A,
                                                   const float* __restrict__ Bm,
                                                   const float* __restrict__ bias,
                                                   const float* __restrict__ resid,
                                                   const float* __restrict__ alphap,
                                                   float* __restrict__ C,
                                                   int M, int N, int K, int ldb) {
    __shared__ float As[16][65];
    __shared__ float Bs[16][65];
    int m0 = blockIdx.x * 64, n0 = blockIdx.y * 64;
    int tid = threadIdx.x;
    int ty = tid >> 4, tx = tid & 15;
    float acc[4][4] = {};
    for (int k0 = 0; k0 < K; k0 += 16) {
        {   // A tile (64 rows x 16 k), row-major A with lda=K
            int row = tid >> 2, kq = tid & 3;
            float4 av = *reinterpret_cast<const float4*>(&A[(size_t)(m0 + row) * K + k0 + kq * 4]);
            As[kq * 4 + 0][row] = av.x; As[kq * 4 + 1][row] = av.y;
            As[kq * 4 + 2][row] = av.z; As[kq * 4 + 3][row] = av.w;
        }
        if (!BT) {  // B[k][n] = Bm[k*ldb + n]
            int kk = tid >> 4, nq = tid & 15;
            float4 bv = *reinterpret_cast<const float4*>(&Bm[(size_t)(k0 + kk) * ldb + n0 + nq * 4]);
            Bs[kk][nq * 4 + 0] = bv.x; Bs[kk][nq * 4 + 1] = bv.y;
            Bs[kk][nq * 4 + 2] = bv.z; Bs[kk][nq * 4 + 3] = bv.w;
        } else {    // B[k][n] = Bm[n*ldb + k]
            int nn = tid >> 2, kq = tid & 3;
            float4 bv = *reinterpret_cast<const float4*>(&Bm[(size_t)(n0 + nn) * ldb + k0 + kq * 4]);
            Bs[kq * 4 + 0][nn] = bv.x; Bs[kq * 4 + 1][nn] = bv.y;
            Bs[kq * 4 + 2][nn] = bv.z; Bs[kq * 4 + 3][nn] = bv.w;
        }
        __syncthreads();
#pragma unroll
        for (int kk = 0; kk < 16; ++kk) {
            float ar[4], br[4];
#pragma unroll
            for (int i = 0; i < 4; ++i) ar[i] = As[kk][ty * 4 + i];
#pragma unroll
            for (int j = 0; j < 4; ++j) br[j] = Bs[kk][tx * 4 + j];
#pragma unroll
            for (int i = 0; i < 4; ++i)
#pragma unroll
                for (int j = 0; j < 4; ++j) acc[i][j] += ar[i] * br[j];
        }
        __syncthreads();
    }
    float alpha = (EPI == 2) ? alphap[0] : 0.f;
#pragma unroll
    for (int i = 0; i < 4; ++i) {
        int m = m0 + ty * 4 + i;
#pragma unroll
        for (int j = 0; j < 4; ++j) {
            int n = n0 + tx * 4 + j;
            float v = acc[i][j];
            if (EPI == 1) v += bias[n];
            else if (EPI == 2) v = resid[(size_t)m * N + n] + alpha * (v + bias[n]);
            else if (EPI == 3) { v += bias[n]; v = 0.5f * v * (1.f + erff(v * 0.70710678118f)); }
            else if (EPI == 4) v = resid[(size_t)m * N + n] + v + bias[n];
            C[(size_t)m * N + n] = v;
        }
    }
}

// ---------------- attention: one block per (b, head) ----------------
__global__ __launch_bounds__(256) void attn_kernel(const float* __restrict__ qkv,
                                                   const float* __restrict__ rpb,
                                                   float* __restrict__ o) {
    int bh = blockIdx.x;
    int b = bh >> 2, h = bh & 3;
    __shared__ float Q[64][HD], Kt[64][HD], V[64][HD];
    __shared__ float S[64][64];
    const float* base = qkv + (size_t)b * NP * (3 * TD) + h * HD;
    for (int e = threadIdx.x; e < 64 * HD; e += 256) {
        int n = e / HD, d = e % HD;
        Q[n][d]  = base[(size_t)n * (3 * TD) + d];
        Kt[n][d] = base[(size_t)n * (3 * TD) + TD + d];
        V[n][d]  = base[(size_t)n * (3 * TD) + 2 * TD + d];
    }
    __syncthreads();
    const float scale = 0.14433756729740643f;  // 1/sqrt(48)
    for (int e = threadIdx.x; e < 4096; e += 256) {
        int n = e >> 6, m = e & 63;
        float acc = 0.f;
#pragma unroll
        for (int d = 0; d < HD; ++d) acc += Q[n][d] * Kt[m][d];
        int rel0 = (n >> 3) - (m >> 3), rel1 = (n & 7) - (m & 7);
        int idx = (rel0 + 7) * 15 + (rel1 + 7);
        S[n][m] = acc * scale + rpb[idx * NH + h];
    }
    __syncthreads();
    {   // softmax, 4 threads per row
        int n = threadIdx.x >> 2, j = threadIdx.x & 3;
        float mx = -1e30f;
        for (int m = j; m < 64; m += 4) mx = fmaxf(mx, S[n][m]);
#pragma unroll
        for (int o2 = 1; o2 < 4; o2 <<= 1) mx = fmaxf(mx, __shfl_xor(mx, o2));
        float sum = 0.f;
        for (int m = j; m < 64; m += 4) { float e2 = expf(S[n][m] - mx); S[n][m] = e2; sum += e2; }
#pragma unroll
        for (int o2 = 1; o2 < 4; o2 <<= 1) sum += __shfl_xor(sum, o2);
        float inv = 1.f / sum;
        for (int m = j; m < 64; m += 4) S[n][m] *= inv;
    }
    __syncthreads();
    for (int e = threadIdx.x; e < 64 * HD; e += 256) {
        int n = e / HD, d = e % HD;
        float acc = 0.f;
#pragma unroll
        for (int m = 0; m < 64; ++m) acc += S[n][m] * V[m][d];
        o[((size_t)b * NP + n) * TD + h * HD + d] = acc;
    }
}

// ---------------- final: out[b,c,h,w] = x[b,c,h,w] + y[b,patch(h,w),c] ----------------
__global__ __launch_bounds__(256) void final_kernel(const float* __restrict__ x,
                                                    const float* __restrict__ y,
                                                    float* __restrict__ out) {
    size_t g = (size_t)blockIdx.x * 256 + threadIdx.x;  // over B*C*H*W/4
    int w4 = g & 7, hh = (g >> 3) & 31, c = (g >> 8) & 255, b = (int)(g >> 16);
    int p = (hh >> 2) * 8 + w4;
    float yv = y[((size_t)b * NP + p) * Cch + c];
    float4 xv = reinterpret_cast<const float4*>(x)[g];
    float4 ov = make_float4(xv.x + yv, xv.y + yv, xv.z + yv, xv.w + yv);
    reinterpret_cast<float4*>(out)[g] = ov;
}

extern "C" void kernel_launch(void* const* d_in, const int* in_sizes, int n_in,
                              void* d_out, int out_size, void* d_ws, size_t ws_size,
                              hipStream_t stream) {
    const float* x       = (const float*)d_in[0];
    const float* conv1_w = (const float*)d_in[1];
    const float* conv2_w = (const float*)d_in[2];
    const float* qkv_w   = (const float*)d_in[3];
    const float* qkv_b   = (const float*)d_in[4];
    const float* proj_w  = (const float*)d_in[5];
    const float* proj_b  = (const float*)d_in[6];
    const float* ffn_w1  = (const float*)d_in[7];
    const float* ffn_b1  = (const float*)d_in[8];
    const float* ffn_w2  = (const float*)d_in[9];
    const float* ffn_b2  = (const float*)d_in[10];
    const float* ln1_g   = (const float*)d_in[11];
    const float* ln1_b   = (const float*)d_in[12];
    const float* ln2_g   = (const float*)d_in[13];
    const float* ln2_b   = (const float*)d_in[14];
    const float* alpha   = (const float*)d_in[15];
    const float* rpb     = (const float*)d_in[16];
    float* out = (float*)d_out;

    float* ws = (float*)d_ws;
    // workspace layout (floats)
    float* xm   = ws + 0;           // 2,097,152  (8192x256)  later: o, t2, out2
    float* tok  = ws + 2097152;     // 1,572,864  (8192x192)  later: y (extends into h)
    float* qkvb = ws + 3670016;     // 4,718,592  (8192x576)  later: h
    float* tln  = ws + 8388608;     // 1,572,864  (8192x192)  later: out
    float* obuf = xm;               // after xm dead
    float* outb = tln;              // after tln dead
    float* hbuf = qkvb;             // after qkv dead (3,145,728 fits)
    float* t2   = xm;               // after obuf dead
    float* out2 = xm;               // after t2 dead
    float* ybuf = tok;              // after tok/h dead (2,097,152 fits into tok+h span)

    // K1: patch mean of x  -> xm [8192,256]
    patchmean_kernel<<<8192, 256, 0, stream>>>(x, xm);
    // K2: tokens = xm @ conv1_w^T  [8192,192]
    gemm_kernel<true, 0><<<dim3(128, 3), 256, 0, stream>>>(xm, conv1_w, nullptr, nullptr, nullptr,
                                                           tok, NTOK, TD, Cch, Cch);
    // K3a: t = LN1(tokens)
    ln_kernel<<<NTOK, 64, 0, stream>>>(tok, ln1_g, ln1_b, tln);
    // K3b: qkv = t @ qkv_w + qkv_b  [8192,576]
    gemm_kernel<false, 1><<<dim3(128, 9), 256, 0, stream>>>(tln, qkv_w, qkv_b, nullptr, nullptr,
                                                            qkvb, NTOK, 3 * TD, TD, 3 * TD);
    // K4: attention -> o [8192,192]
    attn_kernel<<<Bsz * NH, 256, 0, stream>>>(qkvb, rpb, obuf);
    // K5: out = tokens + alpha*(o @ proj_w + proj_b)
    gemm_kernel<false, 2><<<dim3(128, 3), 256, 0, stream>>>(obuf, proj_w, proj_b, tok, alpha,
                                                            outb, NTOK, TD, TD, TD);
    // K6a: t2 = LN2(out)
    ln_kernel<<<NTOK, 64, 0, stream>>>(outb, ln2_g, ln2_b, t2);
    // K6b: h = gelu(t2 @ ffn_w1 + ffn_b1)  [8192,384]
    gemm_kernel<false, 3><<<dim3(128, 6), 256, 0, stream>>>(t2, ffn_w1, ffn_b1, nullptr, nullptr,
                                                            hbuf, NTOK, FF, TD, FF);
    // K7: out2 = out + h @ ffn_w2 + ffn_b2
    gemm_kernel<false, 4><<<dim3(128, 3), 256, 0, stream>>>(hbuf, ffn_w2, ffn_b2, outb, nullptr,
                                                            out2, NTOK, TD, FF, TD);
    // K8a: y = out2 @ conv2_w^T  [8192,256]
    gemm_kernel<true, 0><<<dim3(128, 4), 256, 0, stream>>>(out2, conv2_w, nullptr, nullptr, nullptr,
                                                           ybuf, NTOK, Cch, TD, TD);
    // K8b: out = x + broadcast(y)
    final_kernel<<<(Bsz * Cch * Him * Wim) / 1024, 256, 0, stream>>>(x, ybuf, out);
}

// Round 2
// 201.393 us; speedup vs baseline: 1.5168x; 1.5168x over previous
//
#include <hip/hip_runtime.h>
#include <hip/hip_bf16.h>

// Problem dims
#define Bsz 128
#define Cch 256
#define Him 32
#define Wim 32
#define TD 192
#define NH 4
#define HD 48
#define FF 384
#define NP 64            // 8x8 patches
#define NTOK (Bsz*NP)    // 8192 token rows

typedef float f32x4 __attribute__((ext_vector_type(4)));
typedef __bf16 bf16x8 __attribute__((ext_vector_type(8)));

__device__ __forceinline__ ushort f2bf(float f) {
    union { __hip_bfloat16 h; ushort u; } cv;
    cv.h = __float2bfloat16(f);
    return cv.u;
}

// ---------------- weight prep: convert (+transpose) all weights to bf16 Wt[n][k] ----------------
// layout in wb (ushort elems): c1[0,49152) c2[49152,98304) qkvT[98304,208896)
//                              projT[208896,245760) ffn1T[245760,319488) ffn2T[319488,393216)
__global__ __launch_bounds__(256) void wprep_kernel(const float* __restrict__ c1,
                                                    const float* __restrict__ c2,
                                                    const float* __restrict__ qw,
                                                    const float* __restrict__ pw,
                                                    const float* __restrict__ f1,
                                                    const float* __restrict__ f2,
                                                    ushort* __restrict__ wb) {
    int g = blockIdx.x * 256 + threadIdx.x;  // 393216 total
    float v;
    if (g < 49152) v = c1[g];                                   // conv1_w [192][256] already [N][K]
    else if (g < 98304) v = c2[g - 49152];                      // conv2_w [256][192] already [N][K]
    else if (g < 208896) { int i = g - 98304;  int n = i / 192, k = i - n * 192; v = qw[k * 576 + n]; }
    else if (g < 245760) { int i = g - 208896; int n = i / 192, k = i - n * 192; v = pw[k * 192 + n]; }
    else if (g < 319488) { int i = g - 245760; int n = i / 192, k = i - n * 192; v = f1[k * 384 + n]; }
    else                 { int i = g - 319488; int n = i / 384, k = i - n * 384; v = f2[k * 192 + n]; }
    wb[g] = f2bf(v);
}

// ---------------- patch mean: xm[b,p,c] = mean_{4x4} x[b,c,...] -> bf16 ----------------
__global__ __launch_bounds__(256) void patchmean_kernel(const float* __restrict__ x,
                                                        ushort* __restrict__ xm) {
    int g = blockIdx.x * 256 + threadIdx.x;        // B*C*64 = 2,097,152
    int nw = g & 7, nh = (g >> 3) & 7, c = (g >> 6) & 255, b = g >> 14;
    const float* px = x + ((size_t)(b * Cch + c) * Him + nh * 4) * Wim + nw * 4;
    float4 s0 = *reinterpret_cast<const float4*>(px);
    float4 s1 = *reinterpret_cast<const float4*>(px + Wim);
    float4 s2 = *reinterpret_cast<const float4*>(px + 2 * Wim);
    float4 s3 = *reinterpret_cast<const float4*>(px + 3 * Wim);
    float s = s0.x + s0.y + s0.z + s0.w + s1.x + s1.y + s1.z + s1.w +
              s2.x + s2.y + s2.z + s2.w + s3.x + s3.y + s3.z + s3.w;
    xm[(size_t)(b * NP + nh * 8 + nw) * Cch + c] = f2bf(s * 0.0625f);
}

// ---------------- LayerNorm over TD=192, one wave per row, bf16 out ----------------
__global__ __launch_bounds__(64) void ln_kernel(const float* __restrict__ in,
                                                const float* __restrict__ g,
                                                const float* __restrict__ bta,
                                                ushort* __restrict__ out) {
    int r = blockIdx.x, t = threadIdx.x;
    const float* row = in + (size_t)r * TD;
    float v0 = row[t], v1 = row[t + 64], v2 = row[t + 128];
    float s = v0 + v1 + v2;
    float s2 = v0 * v0 + v1 * v1 + v2 * v2;
    for (int o = 32; o; o >>= 1) { s += __shfl_down(s, o); s2 += __shfl_down(s2, o); }
    s = __shfl(s, 0); s2 = __shfl(s2, 0);
    float mean = s * (1.0f / TD);
    float var = s2 * (1.0f / TD) - mean * mean;
    float inv = rsqrtf(var + 1e-5f);
    ushort* orow = out + (size_t)r * TD;
    orow[t]       = f2bf((v0 - mean) * inv * g[t]       + bta[t]);
    orow[t + 64]  = f2bf((v1 - mean) * inv * g[t + 64]  + bta[t + 64]);
    orow[t + 128] = f2bf((v2 - mean) * inv * g[t + 128] + bta[t + 128]);
}

// ---------------- MFMA bf16 GEMM: C[M,N] = A[M,K](bf16) @ Wt[N,K](bf16)^T + epilogue ----------------
// BM=64, BN=64, 256 threads = 4 waves, wave w owns rows [w*16, w*16+16)
// EPI: 0 none; 1 +bias; 2 resid + alpha*(acc+bias); 3 gelu(acc+bias); 4 resid+acc+bias
// OD: 0 f32 out, 1 bf16 out
template <int EPI, int OD>
__global__ __launch_bounds__(256) void mgemm(const ushort* __restrict__ A,
                                             const ushort* __restrict__ Wt,
                                             const float* __restrict__ bias,
                                             const float* __restrict__ resid,
                                             const float* __restrict__ alphap,
                                             void* __restrict__ Cout,
                                             int M, int N, int K) {
    // A tile in LDS: k-slot planes [4][64 rows][8 bf16], plane padded to 65 rows (bank spread)
    __shared__ __align__(16) ushort ldsA[4][65][8];
    const int tid = threadIdx.x;
    const int lane = tid & 63, w = tid >> 6;
    const int m0 = blockIdx.x * 64, n0 = blockIdx.y * 64;
    const int nk = K >> 5;
    const int srow = tid & 63, skslot = tid >> 6;
    const ushort* Ap = A + (size_t)(m0 + srow) * K + skslot * 8;
    const int arow = w * 16 + (lane & 15);
    const int akslot = lane >> 4;
    const ushort* Bp0 = Wt + (size_t)(n0 + (lane & 15)) * K + (lane >> 4) * 8;

    f32x4 acc[4] = {{0,0,0,0},{0,0,0,0},{0,0,0,0},{0,0,0,0}};
    uint4 sv = *reinterpret_cast<const uint4*>(Ap);
    for (int ks = 0; ks < nk; ++ks) {
        *reinterpret_cast<uint4*>(&ldsA[skslot][srow][0]) = sv;
        if (ks + 1 < nk) sv = *reinterpret_cast<const uint4*>(Ap + (ks + 1) * 32);
        __syncthreads();
        bf16x8 af = *reinterpret_cast<const bf16x8*>(&ldsA[akslot][arow][0]);
        const ushort* Bp = Bp0 + ks * 32;
#pragma unroll
        for (int nf = 0; nf < 4; ++nf) {
            bf16x8 bfr = *reinterpret_cast<const bf16x8*>(Bp + (size_t)nf * 16 * K);
            acc[nf] = __builtin_amdgcn_mfma_f32_16x16x32_bf16(af, bfr, acc[nf], 0, 0, 0);
        }
        __syncthreads();
    }
    const float alpha = (EPI == 2) ? alphap[0] : 0.f;
    const int orow = m0 + w * 16 + ((lane >> 4) << 2);
    const int ocol0 = n0 + (lane & 15);
#pragma unroll
    for (int nf = 0; nf < 4; ++nf) {
        int col = ocol0 + nf * 16;
        float bv = (EPI >= 1) ? bias[col] : 0.f;
#pragma unroll
        for (int r = 0; r < 4; ++r) {
            int row = orow + r;
            float v = acc[nf][r];
            if (EPI == 1) v += bv;
            else if (EPI == 2) v = resid[(size_t)row * N + col] + alpha * (v + bv);
            else if (EPI == 3) { v += bv; v = 0.5f * v * (1.f + erff(v * 0.70710678118f)); }
            else if (EPI == 4) v = resid[(size_t)row * N + col] + v + bv;
            if (OD == 0) ((float*)Cout)[(size_t)row * N + col] = v;
            else         ((ushort*)Cout)[(size_t)row * N + col] = f2bf(v);
        }
    }
}

// ---------------- attention: one block per (b, head), f32 math, bf16 out ----------------
__global__ __launch_bounds__(256) void attn_kernel(const float* __restrict__ qkv,
                                                   const float* __restrict__ rpb,
                                                   ushort* __restrict__ o) {
    int bh = blockIdx.x;
    int b = bh >> 2, h = bh & 3;
    __shared__ float Q[64][HD];       // broadcast reads -> no pad needed
    __shared__ float Kt[64][68];      // padded: lanes read different rows
    __shared__ float V[64][HD];       // broadcast reads
    __shared__ float S[64][65];       // padded: PV reads different rows per lane
    const float* base = qkv + (size_t)b * NP * (3 * TD) + h * HD;
    for (int e = threadIdx.x; e < 64 * 12; e += 256) {
        int n = e / 12, d4 = (e % 12) * 4;
        const float* bq = base + (size_t)n * (3 * TD);
        *reinterpret_cast<float4*>(&Q[n][d4])  = *reinterpret_cast<const float4*>(bq + d4);
        *reinterpret_cast<float4*>(&Kt[n][d4]) = *reinterpret_cast<const float4*>(bq + TD + d4);
        *reinterpret_cast<float4*>(&V[n][d4])  = *reinterpret_cast<const float4*>(bq + 2 * TD + d4);
    }
    __syncthreads();
    const float scale = 0.14433756729740643f;  // 1/sqrt(48)
    for (int e = threadIdx.x; e < 4096; e += 256) {
        int n = e >> 6, m = e & 63;
        float acc = 0.f;
#pragma unroll
        for (int d = 0; d < HD; d += 4) {
            float4 qv = *reinterpret_cast<const float4*>(&Q[n][d]);
            float4 kv = *reinterpret_cast<const float4*>(&Kt[m][d]);
            acc += qv.x * kv.x + qv.y * kv.y + qv.z * kv.z + qv.w * kv.w;
        }
        int rel0 = (n >> 3) - (m >> 3), rel1 = (n & 7) - (m & 7);
        int idx = (rel0 + 7) * 15 + (rel1 + 7);
        S[n][m] = acc * scale + rpb[idx * NH + h];
    }
    __syncthreads();
    {   // softmax, 4 threads per row
        int n = threadIdx.x >> 2, j = threadIdx.x & 3;
        float mx = -1e30f;
        for (int m = j; m < 64; m += 4) mx = fmaxf(mx, S[n][m]);
#pragma unroll
        for (int o2 = 1; o2 < 4; o2 <<= 1) mx = fmaxf(mx, __shfl_xor(mx, o2));
        float sum = 0.f;
        for (int m = j; m < 64; m += 4) { float e2 = expf(S[n][m] - mx); S[n][m] = e2; sum += e2; }
#pragma unroll
        for (int o2 = 1; o2 < 4; o2 <<= 1) sum += __shfl_xor(sum, o2);
        float inv = 1.f / sum;
        for (int m = j; m < 64; m += 4) S[n][m] *= inv;
    }
    __syncthreads();
    for (int e = threadIdx.x; e < 64 * 12; e += 256) {
        int n = e / 12, dd = (e % 12) * 4;
        float a0 = 0.f, a1 = 0.f, a2 = 0.f, a3 = 0.f;
#pragma unroll 8
        for (int m = 0; m < 64; ++m) {
            float s = S[n][m];
            float4 v4 = *reinterpret_cast<const float4*>(&V[m][dd]);
            a0 += s * v4.x; a1 += s * v4.y; a2 += s * v4.z; a3 += s * v4.w;
        }
        ushort4 r; r.x = f2bf(a0); r.y = f2bf(a1); r.z = f2bf(a2); r.w = f2bf(a3);
        *reinterpret_cast<ushort4*>(o + ((size_t)(b * NP + n)) * TD + h * HD + dd) = r;
    }
}

// ---------------- final: out[b,c,h,w] = x[b,c,h,w] + y[b,patch(h,w),c] ----------------
__global__ __launch_bounds__(256) void final_kernel(const float* __restrict__ x,
                                                    const float* __restrict__ y,
                                                    float* __restrict__ out) {
    size_t g = (size_t)blockIdx.x * 256 + threadIdx.x;  // over B*C*H*W/4
    int w4 = g & 7, hh = (g >> 3) & 31, c = (g >> 8) & 255, b = (int)(g >> 16);
    int p = (hh >> 2) * 8 + w4;
    float yv = y[((size_t)b * NP + p) * Cch + c];
    float4 xv = reinterpret_cast<const float4*>(x)[g];
    float4 ov = make_float4(xv.x + yv, xv.y + yv, xv.z + yv, xv.w + yv);
    reinterpret_cast<float4*>(out)[g] = ov;
}

extern "C" void kernel_launch(void* const* d_in, const int* in_sizes, int n_in,
                              void* d_out, int out_size, void* d_ws, size_t ws_size,
                              hipStream_t stream) {
    const float* x       = (const float*)d_in[0];
    const float* conv1_w = (const float*)d_in[1];
    const float* conv2_w = (const float*)d_in[2];
    const float* qkv_w   = (const float*)d_in[3];
    const float* qkv_b   = (const float*)d_in[4];
    const float* proj_w  = (const float*)d_in[5];
    const float* proj_b  = (const float*)d_in[6];
    const float* ffn_w1  = (const float*)d_in[7];
    const float* ffn_b1  = (const float*)d_in[8];
    const float* ffn_w2  = (const float*)d_in[9];
    const float* ffn_b2  = (const float*)d_in[10];
    const float* ln1_g   = (const float*)d_in[11];
    const float* ln1_b   = (const float*)d_in[12];
    const float* ln2_g   = (const float*)d_in[13];
    const float* ln2_b   = (const float*)d_in[14];
    const float* alpha   = (const float*)d_in[15];
    const float* rpb     = (const float*)d_in[16];
    float* out = (float*)d_out;

    // workspace layout
    float* ws_f = (float*)d_ws;
    float*  tok  = ws_f;                    // 8192*192 f32
    float*  outb = ws_f + 1572864;          // 8192*192 f32
    float*  qkvb = ws_f + 3145728;          // 8192*576 f32
    float*  ybuf = ws_f + 7864320;          // 8192*256 f32
    ushort* us   = (ushort*)(ws_f + 9961472);
    ushort* xm   = us;                      // 8192*256 bf16
    ushort* tln  = us + 2097152;            // 8192*192
    ushort* obf  = us + 3670016;            // 8192*192
    ushort* t2   = us + 5242880;            // 8192*192
    ushort* hbf  = us + 6815744;            // 8192*384
    ushort* out2 = us + 9961472;            // 8192*192
    ushort* wb   = us + 11534336;           // 393216 weights
    ushort* c1bf  = wb;
    ushort* c2bf  = wb + 49152;
    ushort* qkvT  = wb + 98304;
    ushort* projT = wb + 208896;
    ushort* f1T   = wb + 245760;
    ushort* f2T   = wb + 319488;

    // K0: weights -> bf16 (transposed to [N][K] where needed)
    wprep_kernel<<<1536, 256, 0, stream>>>(conv1_w, conv2_w, qkv_w, proj_w, ffn_w1, ffn_w2, wb);
    // K1: patch mean of x -> xm bf16 [8192,256]
    patchmean_kernel<<<8192, 256, 0, stream>>>(x, xm);
    // K2: tokens = xm @ conv1_w^T -> f32 [8192,192]
    mgemm<0, 0><<<dim3(128, 3), 256, 0, stream>>>(xm, c1bf, nullptr, nullptr, nullptr,
                                                  tok, NTOK, TD, Cch);
    // K3a: tln = LN1(tokens) -> bf16
    ln_kernel<<<NTOK, 64, 0, stream>>>(tok, ln1_g, ln1_b, tln);
    // K3b: qkv = tln @ qkv_w + qkv_b -> f32 [8192,576]
    mgemm<1, 0><<<dim3(128, 9), 256, 0, stream>>>(tln, qkvT, qkv_b, nullptr, nullptr,
                                                  qkvb, NTOK, 3 * TD, TD);
    // K4: attention -> obf bf16 [8192,192]
    attn_kernel<<<Bsz * NH, 256, 0, stream>>>(qkvb, rpb, obf);
    // K5: out = tokens + alpha*(o @ proj_w + proj_b) -> f32
    mgemm<2, 0><<<dim3(128, 3), 256, 0, stream>>>(obf, projT, proj_b, tok, alpha,
                                                  outb, NTOK, TD, TD);
    // K6a: t2 = LN2(out) -> bf16
    ln_kernel<<<NTOK, 64, 0, stream>>>(outb, ln2_g, ln2_b, t2);
    // K6b: h = gelu(t2 @ ffn_w1 + ffn_b1) -> bf16 [8192,384]
    mgemm<3, 1><<<dim3(128, 6), 256, 0, stream>>>(t2, f1T, ffn_b1, nullptr, nullptr,
                                                  hbf, NTOK, FF, TD);
    // K7: out2 = out + h @ ffn_w2 + ffn_b2 -> bf16
    mgemm<4, 1><<<dim3(128, 3), 256, 0, stream>>>(hbf, f2T, ffn_b2, outb, nullptr,
                                                  out2, NTOK, TD, FF);
    // K8a: y = out2 @ conv2_w^T -> f32 [8192,256]
    mgemm<0, 0><<<dim3(128, 4), 256, 0, stream>>>(out2, c2bf, nullptr, nullptr, nullptr,
                                                  ybuf, NTOK, Cch, TD);
    // K8b: out = x + broadcast(y)
    final_kernel<<<(Bsz * Cch * Him * Wim) / 1024, 256, 0, stream>>>(x, ybuf, out);
}

// Round 3
// 185.802 us; speedup vs baseline: 1.6440x; 1.0839x over previous
//
#include <hip/hip_runtime.h>
#include <hip/hip_bf16.h>

// Problem dims
#define Bsz 128
#define Cch 256
#define Him 32
#define Wim 32
#define TD 192
#define NH 4
#define HD 48
#define FF 384
#define NP 64            // 8x8 patches
#define NTOK (Bsz*NP)    // 8192 token rows

typedef float f32x4 __attribute__((ext_vector_type(4)));
typedef __bf16 bf16x8 __attribute__((ext_vector_type(8)));

__device__ __forceinline__ ushort f2bf(float f) {
    union { __hip_bfloat16 h; ushort u; } cv;
    cv.h = __float2bfloat16(f);
    return cv.u;
}

// ---------------- weight prep: convert (+transpose) all weights to bf16 Wt[n][k] ----------------
// layout in wb (ushort elems): c1[0,49152) c2[49152,98304) qkvT[98304,208896)
//                              projT[208896,245760) ffn1T[245760,319488) ffn2T[319488,393216)
__global__ __launch_bounds__(256) void wprep_kernel(const float* __restrict__ c1,
                                                    const float* __restrict__ c2,
                                                    const float* __restrict__ qw,
                                                    const float* __restrict__ pw,
                                                    const float* __restrict__ f1,
                                                    const float* __restrict__ f2,
                                                    ushort* __restrict__ wb) {
    int g = blockIdx.x * 256 + threadIdx.x;  // 393216 total
    float v;
    if (g < 49152) v = c1[g];                                   // conv1_w [192][256] already [N][K]
    else if (g < 98304) v = c2[g - 49152];                      // conv2_w [256][192] already [N][K]
    else if (g < 208896) { int i = g - 98304;  int n = i / 192, k = i - n * 192; v = qw[k * 576 + n]; }
    else if (g < 245760) { int i = g - 208896; int n = i / 192, k = i - n * 192; v = pw[k * 192 + n]; }
    else if (g < 319488) { int i = g - 245760; int n = i / 192, k = i - n * 192; v = f1[k * 384 + n]; }
    else                 { int i = g - 319488; int n = i / 384, k = i - n * 384; v = f2[k * 192 + n]; }
    wb[g] = f2bf(v);
}

// ---------------- patch mean: xm[b,p,c] = mean_{4x4} x[b,c,...] -> bf16 ----------------
__global__ __launch_bounds__(256) void patchmean_kernel(const float* __restrict__ x,
                                                        ushort* __restrict__ xm) {
    int g = blockIdx.x * 256 + threadIdx.x;        // B*C*64 = 2,097,152
    int nw = g & 7, nh = (g >> 3) & 7, c = (g >> 6) & 255, b = g >> 14;
    const float* px = x + ((size_t)(b * Cch + c) * Him + nh * 4) * Wim + nw * 4;
    float4 s0 = *reinterpret_cast<const float4*>(px);
    float4 s1 = *reinterpret_cast<const float4*>(px + Wim);
    float4 s2 = *reinterpret_cast<const float4*>(px + 2 * Wim);
    float4 s3 = *reinterpret_cast<const float4*>(px + 3 * Wim);
    float s = s0.x + s0.y + s0.z + s0.w + s1.x + s1.y + s1.z + s1.w +
              s2.x + s2.y + s2.z + s2.w + s3.x + s3.y + s3.z + s3.w;
    xm[(size_t)(b * NP + nh * 8 + nw) * Cch + c] = f2bf(s * 0.0625f);
}

// ---------------- GEMM inner helper: acc[NF] += A(16 rows)x32k * B(NF*16 cols)x32k ----------------
// a0: lane's A row pointer (+kslot*8 already applied); b0: lane's B col pointer (+kslot*8)
template <int NF, int NK>
__device__ __forceinline__ void mm(const ushort* __restrict__ a0,
                                   const ushort* __restrict__ b0,
                                   int bstride, f32x4* acc) {
#pragma unroll
    for (int kk = 0; kk < NK; ++kk) {
        bf16x8 af = *reinterpret_cast<const bf16x8*>(a0 + kk * 32);
#pragma unroll
        for (int nf = 0; nf < NF; ++nf) {
            bf16x8 bfr = *reinterpret_cast<const bf16x8*>(b0 + (size_t)nf * bstride + kk * 32);
            acc[nf] = __builtin_amdgcn_mfma_f32_16x16x32_bf16(af, bfr, acc[nf], 0, 0, 0);
        }
    }
}

// ---------------- mega token kernel: one block per image, 8 waves ----------------
// LDS map (131072 B):
//  [0,25600)        tln [64][200]     -> P2 [2][64][72] -> h0 [64][200]
//  [25600,51200)    q   [64][200]     -> outf [64][196] f32 (spans into k region)
//  [51200,76800)    k   [64][200]
//  [76800,104448)   vT  [192][72]     -> t2 [64][200]  -> o2 [64][200]
//  [104448,130048)  o   [64][200]     -> h1 [64][200]
//  [130048,131072)  scr (256 f32)
__global__ __launch_bounds__(512, 1) void mega_kernel(
    const ushort* __restrict__ xm, const ushort* __restrict__ wb,
    const float* __restrict__ qkv_b, const float* __restrict__ proj_b,
    const float* __restrict__ ffn_b1, const float* __restrict__ ffn_b2,
    const float* __restrict__ ln1_g, const float* __restrict__ ln1_b,
    const float* __restrict__ ln2_g, const float* __restrict__ ln2_b,
    const float* __restrict__ alphap, const float* __restrict__ rpb,
    float* __restrict__ tokg, float* __restrict__ y) {
    __shared__ __align__(16) char LDS[131072];
    ushort* tln  = (ushort*)(LDS);
    ushort* qb   = (ushort*)(LDS + 25600);
    ushort* kb2_ = (ushort*)(LDS + 51200);
    ushort* vT   = (ushort*)(LDS + 76800);
    ushort* ob   = (ushort*)(LDS + 104448);
    ushort* P2   = (ushort*)(LDS);
    float*  outf = (float*)(LDS + 25600);
    ushort* t2   = (ushort*)(LDS + 76800);
    ushort* h0   = (ushort*)(LDS);
    ushort* h1   = (ushort*)(LDS + 104448);
    ushort* o2   = (ushort*)(LDS + 76800);
    float*  scr  = (float*)(LDS + 130048);

    const int b = blockIdx.x;
    const int tid = threadIdx.x, lane = tid & 63, w = tid >> 6;
    const int l15 = lane & 15, slot = lane >> 4;
    const int r = w >> 1, cc = w & 1;
    const int rowA = r * 16 + l15;          // A-frag row (M-row for MFMA input)
    // C-layout rows: r*16 + slot*4 + j ; cols: l15 + nf*16 (+ wave col base)

    // ---- Ph1: conv1 (tokens = xm @ c1^T) + fused LN1 ----
    {
        f32x4 acc[6] = {};
        const ushort* a0 = xm + ((size_t)(b * 64 + rowA)) * 256 + slot * 8;
        const ushort* b0 = wb + ((size_t)(cc * 96 + l15)) * 256 + slot * 8;
        mm<6, 8>(a0, b0, 16 * 256, acc);
        float s[4] = {}, s2[4] = {};
#pragma unroll
        for (int nf = 0; nf < 6; ++nf)
#pragma unroll
            for (int j = 0; j < 4; ++j) {
                float v = acc[nf][j];
                int row = r * 16 + slot * 4 + j;
                int col = cc * 96 + l15 + nf * 16;
                tokg[((size_t)(b * 64 + row)) * 192 + col] = v;
                s[j] += v; s2[j] += v * v;
            }
#pragma unroll
        for (int m = 1; m < 16; m <<= 1)
#pragma unroll
            for (int j = 0; j < 4; ++j) { s[j] += __shfl_xor(s[j], m); s2[j] += __shfl_xor(s2[j], m); }
        if (l15 == 0)
#pragma unroll
            for (int j = 0; j < 4; ++j) {
                int row = r * 16 + slot * 4 + j;
                scr[row * 2 + cc] = s[j]; scr[128 + row * 2 + cc] = s2[j];
            }
        __syncthreads();
#pragma unroll
        for (int j = 0; j < 4; ++j) {
            int row = r * 16 + slot * 4 + j;
            float ssum = scr[row * 2] + scr[row * 2 + 1];
            float ssq  = scr[128 + row * 2] + scr[128 + row * 2 + 1];
            float mean = ssum * (1.f / 192.f);
            float inv = rsqrtf(ssq * (1.f / 192.f) - mean * mean + 1e-5f);
#pragma unroll
            for (int nf = 0; nf < 6; ++nf) {
                int col = cc * 96 + l15 + nf * 16;
                tln[row * 200 + col] = f2bf((acc[nf][j] - mean) * inv * ln1_g[col] + ln1_b[col]);
            }
        }
    }
    __syncthreads();

    // ---- Ph2-4: q, k, v GEMMs (A = tln; disjoint outputs, one barrier after) ----
    const ushort* qkvT = wb + 98304;
    const ushort* aTln = tln + rowA * 200 + slot * 8;
    {
        f32x4 acc[6] = {};
        mm<6, 6>(aTln, qkvT + ((size_t)(cc * 96 + l15)) * 192 + slot * 8, 16 * 192, acc);
#pragma unroll
        for (int nf = 0; nf < 6; ++nf) {
            int col = cc * 96 + l15 + nf * 16;
            float bias = qkv_b[col];
#pragma unroll
            for (int j = 0; j < 4; ++j)
                qb[(r * 16 + slot * 4 + j) * 200 + col] = f2bf(acc[nf][j] + bias);
        }
    }
    {
        f32x4 acc[6] = {};
        mm<6, 6>(aTln, qkvT + ((size_t)(192 + cc * 96 + l15)) * 192 + slot * 8, 16 * 192, acc);
#pragma unroll
        for (int nf = 0; nf < 6; ++nf) {
            int col = cc * 96 + l15 + nf * 16;
            float bias = qkv_b[192 + col];
#pragma unroll
            for (int j = 0; j < 4; ++j)
                kb2_[(r * 16 + slot * 4 + j) * 200 + col] = f2bf(acc[nf][j] + bias);
        }
    }
    {
        f32x4 acc[6] = {};
        mm<6, 6>(aTln, qkvT + ((size_t)(384 + cc * 96 + l15)) * 192 + slot * 8, 16 * 192, acc);
#pragma unroll
        for (int nf = 0; nf < 6; ++nf) {
            int col = cc * 96 + l15 + nf * 16;
            float bias = qkv_b[384 + col];
            ushort4 pk;
            pk.x = f2bf(acc[nf][0] + bias); pk.y = f2bf(acc[nf][1] + bias);
            pk.z = f2bf(acc[nf][2] + bias); pk.w = f2bf(acc[nf][3] + bias);
            *reinterpret_cast<ushort4*>(&vT[col * 72 + r * 16 + slot * 4]) = pk;  // transposed
        }
    }
    __syncthreads();

    // ---- Ph5: attention, 2 passes x 2 heads (wave -> (r, head-slot cc)) ----
    const float scale = 0.14433756729740643f;  // 1/sqrt(48)
    const int hh = cc;
#pragma unroll 1
    for (int p = 0; p < 2; ++p) {
        int h = p * 2 + hh;
        if (p) __syncthreads();   // P2 reuse across passes
        uint4 z = make_uint4(0, 0, 0, 0);
        const ushort* qrowp = qb + rowA * 200 + h * 48;
        uint4 qa1v = *reinterpret_cast<const uint4*>(qrowp + slot * 8);
        uint4 qa2v = (slot < 2) ? *reinterpret_cast<const uint4*>(qrowp + 32 + slot * 8) : z;
        bf16x8 qaf1 = *reinterpret_cast<bf16x8*>(&qa1v);
        bf16x8 qaf2 = *reinterpret_cast<bf16x8*>(&qa2v);
        f32x4 S[4] = {};
#pragma unroll
        for (int nf = 0; nf < 4; ++nf) {
            const ushort* kp = kb2_ + (l15 + nf * 16) * 200 + h * 48;
            uint4 kb1v = *reinterpret_cast<const uint4*>(kp + slot * 8);
            uint4 kb2v = (slot < 2) ? *reinterpret_cast<const uint4*>(kp + 32 + slot * 8) : z;
            S[nf] = __builtin_amdgcn_mfma_f32_16x16x32_bf16(qaf1, *reinterpret_cast<bf16x8*>(&kb1v), S[nf], 0, 0, 0);
            S[nf] = __builtin_amdgcn_mfma_f32_16x16x32_bf16(qaf2, *reinterpret_cast<bf16x8*>(&kb2v), S[nf], 0, 0, 0);
        }
        // bias + softmax: each row entirely within this wave (16 lanes x 4 nf = 64 cols)
#pragma unroll
        for (int j = 0; j < 4; ++j) {
            int qrow = r * 16 + slot * 4 + j;
            int qh = qrow >> 3, qw = qrow & 7;
            float sv[4];
            float mx = -1e30f;
#pragma unroll
            for (int nf = 0; nf < 4; ++nf) {
                int krow = l15 + nf * 16;
                int idx = (qh - (krow >> 3) + 7) * 15 + (qw - (krow & 7) + 7);
                sv[nf] = S[nf][j] * scale + rpb[idx * 4 + h];
                mx = fmaxf(mx, sv[nf]);
            }
#pragma unroll
            for (int m = 1; m < 16; m <<= 1) mx = fmaxf(mx, __shfl_xor(mx, m));
            float sum = 0.f;
#pragma unroll
            for (int nf = 0; nf < 4; ++nf) { sv[nf] = expf(sv[nf] - mx); sum += sv[nf]; }
#pragma unroll
            for (int m = 1; m < 16; m <<= 1) sum += __shfl_xor(sum, m);
            float inv = 1.f / sum;
#pragma unroll
            for (int nf = 0; nf < 4; ++nf)
                P2[hh * 4608 + qrow * 72 + l15 + nf * 16] = f2bf(sv[nf] * inv);
        }
        __syncthreads();
        // PV: o[rows r*16..][h*48..+48] = P @ V
        f32x4 O[3] = {};
        const ushort* prow = P2 + hh * 4608 + rowA * 72 + slot * 8;
#pragma unroll
        for (int ki = 0; ki < 2; ++ki) {
            bf16x8 pa = *reinterpret_cast<const bf16x8*>(prow + ki * 32);
#pragma unroll
            for (int nf = 0; nf < 3; ++nf) {
                bf16x8 vb = *reinterpret_cast<const bf16x8*>(&vT[(h * 48 + l15 + nf * 16) * 72 + ki * 32 + slot * 8]);
                O[nf] = __builtin_amdgcn_mfma_f32_16x16x32_bf16(pa, vb, O[nf], 0, 0, 0);
            }
        }
#pragma unroll
        for (int nf = 0; nf < 3; ++nf)
#pragma unroll
            for (int j = 0; j < 4; ++j)
                ob[(r * 16 + slot * 4 + j) * 200 + h * 48 + l15 + nf * 16] = f2bf(O[nf][j]);
    }
    __syncthreads();

    // ---- Ph6: proj + residual + fused LN2 ----
    {
        const float alpha = alphap[0];
        f32x4 acc[6] = {};
        mm<6, 6>(ob + rowA * 200 + slot * 8,
                 wb + 208896 + ((size_t)(cc * 96 + l15)) * 192 + slot * 8, 16 * 192, acc);
        float outv[6][4];
        float s[4] = {}, s2[4] = {};
#pragma unroll
        for (int j = 0; j < 4; ++j) {
            int row = r * 16 + slot * 4 + j;
#pragma unroll
            for (int nf = 0; nf < 6; ++nf) {
                int col = cc * 96 + l15 + nf * 16;
                float v = tokg[((size_t)(b * 64 + row)) * 192 + col] + alpha * (acc[nf][j] + proj_b[col]);
                outv[nf][j] = v;
                outf[row * 196 + col] = v;
                s[j] += v; s2[j] += v * v;
            }
        }
#pragma unroll
        for (int m = 1; m < 16; m <<= 1)
#pragma unroll
            for (int j = 0; j < 4; ++j) { s[j] += __shfl_xor(s[j], m); s2[j] += __shfl_xor(s2[j], m); }
        if (l15 == 0)
#pragma unroll
            for (int j = 0; j < 4; ++j) {
                int row = r * 16 + slot * 4 + j;
                scr[row * 2 + cc] = s[j]; scr[128 + row * 2 + cc] = s2[j];
            }
        __syncthreads();
#pragma unroll
        for (int j = 0; j < 4; ++j) {
            int row = r * 16 + slot * 4 + j;
            float ssum = scr[row * 2] + scr[row * 2 + 1];
            float ssq  = scr[128 + row * 2] + scr[128 + row * 2 + 1];
            float mean = ssum * (1.f / 192.f);
            float inv = rsqrtf(ssq * (1.f / 192.f) - mean * mean + 1e-5f);
#pragma unroll
            for (int nf = 0; nf < 6; ++nf) {
                int col = cc * 96 + l15 + nf * 16;
                t2[row * 200 + col] = f2bf((outv[nf][j] - mean) * inv * ln2_g[col] + ln2_b[col]);
            }
        }
    }
    __syncthreads();

    // ---- Ph7: ffn1 + exact GELU -> h halves ----
    {
        f32x4 acc[12] = {};
        mm<12, 6>(t2 + rowA * 200 + slot * 8,
                  wb + 245760 + ((size_t)(cc * 192 + l15)) * 192 + slot * 8, 16 * 192, acc);
        ushort* hb = cc ? h1 : h0;
#pragma unroll
        for (int nf = 0; nf < 12; ++nf) {
            int lcol = l15 + nf * 16;
            float bias = ffn_b1[cc * 192 + lcol];
#pragma unroll
            for (int j = 0; j < 4; ++j) {
                float v = acc[nf][j] + bias;
                v = 0.5f * v * (1.f + erff(v * 0.70710678118654752f));
                hb[(r * 16 + slot * 4 + j) * 200 + lcol] = f2bf(v);
            }
        }
    }
    __syncthreads();

    // ---- Ph8: ffn2 + residual -> o2 (bf16) ----
    {
        f32x4 acc[6] = {};
        const ushort* b0 = wb + 319488 + ((size_t)(cc * 96 + l15)) * 384 + slot * 8;
        mm<6, 6>(h0 + rowA * 200 + slot * 8, b0, 16 * 384, acc);
        mm<6, 6>(h1 + rowA * 200 + slot * 8, b0 + 192, 16 * 384, acc);
#pragma unroll
        for (int nf = 0; nf < 6; ++nf) {
            int col = cc * 96 + l15 + nf * 16;
            float bias = ffn_b2[col];
#pragma unroll
            for (int j = 0; j < 4; ++j) {
                int row = r * 16 + slot * 4 + j;
                o2[row * 200 + col] = f2bf(outf[row * 196 + col] + acc[nf][j] + bias);
            }
        }
    }
    __syncthreads();

    // ---- Ph9: conv2 -> y (f32, global) ----
    {
        f32x4 acc[8] = {};
        mm<8, 6>(o2 + rowA * 200 + slot * 8,
                 wb + 49152 + ((size_t)(cc * 128 + l15)) * 192 + slot * 8, 16 * 192, acc);
#pragma unroll
        for (int nf = 0; nf < 8; ++nf) {
            int col = cc * 128 + l15 + nf * 16;
#pragma unroll
            for (int j = 0; j < 4; ++j) {
                int row = r * 16 + slot * 4 + j;
                y[((size_t)(b * 64 + row)) * 256 + col] = acc[nf][j];
            }
        }
    }
}

// ---------------- final: out[b,c,h,w] = x[b,c,h,w] + y[b,patch(h,w),c] ----------------
__global__ __launch_bounds__(256) void final_kernel(const float* __restrict__ x,
                                                    const float* __restrict__ y,
                                                    float* __restrict__ out) {
    size_t g = (size_t)blockIdx.x * 256 + threadIdx.x;  // over B*C*H*W/4
    int w4 = g & 7, hh = (g >> 3) & 31, c = (g >> 8) & 255, b = (int)(g >> 16);
    int p = (hh >> 2) * 8 + w4;
    float yv = y[((size_t)b * NP + p) * Cch + c];
    float4 xv = reinterpret_cast<const float4*>(x)[g];
    float4 ov = make_float4(xv.x + yv, xv.y + yv, xv.z + yv, xv.w + yv);
    reinterpret_cast<float4*>(out)[g] = ov;
}

extern "C" void kernel_launch(void* const* d_in, const int* in_sizes, int n_in,
                              void* d_out, int out_size, void* d_ws, size_t ws_size,
                              hipStream_t stream) {
    const float* x       = (const float*)d_in[0];
    const float* conv1_w = (const float*)d_in[1];
    const float* conv2_w = (const float*)d_in[2];
    const float* qkv_w   = (const float*)d_in[3];
    const float* qkv_b   = (const float*)d_in[4];
    const float* proj_w  = (const float*)d_in[5];
    const float* proj_b  = (const float*)d_in[6];
    const float* ffn_w1  = (const float*)d_in[7];
    const float* ffn_b1  = (const float*)d_in[8];
    const float* ffn_w2  = (const float*)d_in[9];
    const float* ffn_b2  = (const float*)d_in[10];
    const float* ln1_g   = (const float*)d_in[11];
    const float* ln1_b   = (const float*)d_in[12];
    const float* ln2_g   = (const float*)d_in[13];
    const float* ln2_b   = (const float*)d_in[14];
    const float* alpha   = (const float*)d_in[15];
    const float* rpb     = (const float*)d_in[16];
    float* out = (float*)d_out;

    // workspace layout
    float* ws_f = (float*)d_ws;
    float*  tokg = ws_f;                     // 8192*192 f32
    float*  ybuf = ws_f + 1572864;           // 8192*256 f32
    ushort* us   = (ushort*)(ws_f + 3670016);
    ushort* xm   = us;                       // 8192*256 bf16
    ushort* wb   = us + 2097152;             // 393216 bf16 weights

    // K0: weights -> bf16 (transposed to [N][K] where needed)
    wprep_kernel<<<1536, 256, 0, stream>>>(conv1_w, conv2_w, qkv_w, proj_w, ffn_w1, ffn_w2, wb);
    // K1: patch mean of x -> xm bf16 [8192,256]
    patchmean_kernel<<<8192, 256, 0, stream>>>(x, xm);
    // K2: whole token pipeline, one block per image
    mega_kernel<<<Bsz, 512, 0, stream>>>(xm, wb, qkv_b, proj_b, ffn_b1, ffn_b2,
                                         ln1_g, ln1_b, ln2_g, ln2_b, alpha, rpb,
                                         tokg, ybuf);
    // K3: out = x + broadcast(y)
    final_kernel<<<(Bsz * Cch * Him * Wim) / 1024, 256, 0, stream>>>(x, ybuf, out);
}

// Round 4
// 184.836 us; speedup vs baseline: 1.6526x; 1.0052x over previous
//
#include <hip/hip_runtime.h>
#include <hip/hip_bf16.h>

// Problem dims
#define Bsz 128
#define Cch 256
#define Him 32
#define Wim 32
#define TD 192
#define NH 4
#define HD 48
#define FF 384
#define NP 64            // 8x8 patches
#define NTOK (Bsz*NP)    // 8192 token rows

typedef float f32x4 __attribute__((ext_vector_type(4)));
typedef __bf16 bf16x8 __attribute__((ext_vector_type(8)));

__device__ __forceinline__ ushort f2bf(float f) {
    union { __hip_bfloat16 h; ushort u; } cv;
    cv.h = __float2bfloat16(f);
    return cv.u;
}

// ---------------- weight prep: convert (+transpose) all weights to bf16 Wt[n][k] ----------------
// layout in wb (ushort elems): c1[0,49152) c2[49152,98304) qkvT[98304,208896)
//                              projT[208896,245760) ffn1T[245760,319488) ffn2T[319488,393216)
__global__ __launch_bounds__(256) void wprep_kernel(const float* __restrict__ c1,
                                                    const float* __restrict__ c2,
                                                    const float* __restrict__ qw,
                                                    const float* __restrict__ pw,
                                                    const float* __restrict__ f1,
                                                    const float* __restrict__ f2,
                                                    ushort* __restrict__ wb) {
    int g = blockIdx.x * 256 + threadIdx.x;  // 393216 total
    float v;
    if (g < 49152) v = c1[g];                                   // conv1_w [192][256] already [N][K]
    else if (g < 98304) v = c2[g - 49152];                      // conv2_w [256][192] already [N][K]
    else if (g < 208896) { int i = g - 98304;  int n = i / 192, k = i - n * 192; v = qw[k * 576 + n]; }
    else if (g < 245760) { int i = g - 208896; int n = i / 192, k = i - n * 192; v = pw[k * 192 + n]; }
    else if (g < 319488) { int i = g - 245760; int n = i / 192, k = i - n * 192; v = f1[k * 384 + n]; }
    else                 { int i = g - 319488; int n = i / 384, k = i - n * 384; v = f2[k * 192 + n]; }
    wb[g] = f2bf(v);
}

// ---------------- patch mean: xm[b,p,c] = mean_{4x4} x[b,c,...] -> bf16 ----------------
__global__ __launch_bounds__(256) void patchmean_kernel(const float* __restrict__ x,
                                                        ushort* __restrict__ xm) {
    int g = blockIdx.x * 256 + threadIdx.x;        // B*C*64 = 2,097,152
    int nw = g & 7, nh = (g >> 3) & 7, c = (g >> 6) & 255, b = g >> 14;
    const float* px = x + ((size_t)(b * Cch + c) * Him + nh * 4) * Wim + nw * 4;
    float4 s0 = *reinterpret_cast<const float4*>(px);
    float4 s1 = *reinterpret_cast<const float4*>(px + Wim);
    float4 s2 = *reinterpret_cast<const float4*>(px + 2 * Wim);
    float4 s3 = *reinterpret_cast<const float4*>(px + 3 * Wim);
    float s = s0.x + s0.y + s0.z + s0.w + s1.x + s1.y + s1.z + s1.w +
              s2.x + s2.y + s2.z + s2.w + s3.x + s3.y + s3.z + s3.w;
    xm[(size_t)(b * NP + nh * 8 + nw) * Cch + c] = f2bf(s * 0.0625f);
}

// ---------------- GEMM inner helper: acc[NF] += A(16 rows)x32k * B(NF*16 cols)x32k ----------------
template <int NF, int NK>
__device__ __forceinline__ void mm(const ushort* __restrict__ a0,
                                   const ushort* __restrict__ b0,
                                   int bstride, f32x4* acc) {
#pragma unroll
    for (int kk = 0; kk < NK; ++kk) {
        bf16x8 af = *reinterpret_cast<const bf16x8*>(a0 + kk * 32);
#pragma unroll
        for (int nf = 0; nf < NF; ++nf) {
            bf16x8 bfr = *reinterpret_cast<const bf16x8*>(b0 + (size_t)nf * bstride + kk * 32);
            acc[nf] = __builtin_amdgcn_mfma_f32_16x16x32_bf16(af, bfr, acc[nf], 0, 0, 0);
        }
    }
}

// ---------------- mega token kernel: one block per image, 16 waves ----------------
// wave w = r*4 + cg : r = row-group (16 rows), cg = col-group (or head in attention)
// LDS map (130048 B):
//  [0,25600)        tln [64][200]        -> scrB (LN2) -> h0 [64][200]
//  [25600,51200)    qb  [64][200]        ; scrA (LN1, pre-qb) ; P [4][64][72] (attn) ; outf f32 [64][196] (spans to 75776)
//  [51200,76800)    kb  [64][200]
//  [76800,104448)   vT  [192][72]        -> t2 [64][200] -> o2 [64][200]
//  [104448,130048)  ob  [64][200]        -> h1 [64][200]
__global__ __launch_bounds__(1024) void mega_kernel(
    const ushort* __restrict__ xm, const ushort* __restrict__ wb,
    const float* __restrict__ qkv_b, const float* __restrict__ proj_b,
    const float* __restrict__ ffn_b1, const float* __restrict__ ffn_b2,
    const float* __restrict__ ln1_g, const float* __restrict__ ln1_b,
    const float* __restrict__ ln2_g, const float* __restrict__ ln2_b,
    const float* __restrict__ alphap, const float* __restrict__ rpb,
    float* __restrict__ tokg, float* __restrict__ y) {
    __shared__ __align__(16) char LDS[130048];
    ushort* tln  = (ushort*)(LDS);
    ushort* qb   = (ushort*)(LDS + 25600);
    ushort* kb   = (ushort*)(LDS + 51200);
    ushort* vT   = (ushort*)(LDS + 76800);
    ushort* ob   = (ushort*)(LDS + 104448);
    ushort* P    = (ushort*)(LDS + 25600);
    float2* scrA = (float2*)(LDS + 25600);
    float2* scrB = (float2*)(LDS);
    float*  outf = (float*)(LDS + 25600);
    ushort* t2   = (ushort*)(LDS + 76800);
    ushort* h0   = (ushort*)(LDS);
    ushort* h1   = (ushort*)(LDS + 104448);
    ushort* o2   = (ushort*)(LDS + 76800);

    const int b = blockIdx.x;
    const int tid = threadIdx.x, lane = tid & 63, w = tid >> 6;
    const int l15 = lane & 15, slot = lane >> 4;
    const int r = w >> 2, cg = w & 3;
    const int rowA = r * 16 + l15;   // A-frag row for MFMA input
    // C-layout: rows r*16 + slot*4 + j ; cols (colbase) + l15 + nf*16

    // ---- Ph1: conv1 (tokens = xm @ c1^T) + fused LN1 ----
    {
        f32x4 acc[3] = {};
        const ushort* a0 = xm + ((size_t)(b * 64 + rowA)) * 256 + slot * 8;
        const ushort* b0 = wb + ((size_t)(cg * 48 + l15)) * 256 + slot * 8;
        mm<3, 8>(a0, b0, 16 * 256, acc);
        float s[4] = {}, s2[4] = {};
#pragma unroll
        for (int nf = 0; nf < 3; ++nf)
#pragma unroll
            for (int j = 0; j < 4; ++j) {
                float v = acc[nf][j];
                int row = r * 16 + slot * 4 + j;
                int col = cg * 48 + l15 + nf * 16;
                tokg[((size_t)(b * 64 + row)) * 192 + col] = v;
                s[j] += v; s2[j] += v * v;
            }
#pragma unroll
        for (int m = 1; m < 16; m <<= 1)
#pragma unroll
            for (int j = 0; j < 4; ++j) { s[j] += __shfl_xor(s[j], m); s2[j] += __shfl_xor(s2[j], m); }
        if (l15 == 0)
#pragma unroll
            for (int j = 0; j < 4; ++j) {
                int row = r * 16 + slot * 4 + j;
                scrA[row * 4 + cg] = make_float2(s[j], s2[j]);
            }
        __syncthreads();
#pragma unroll
        for (int j = 0; j < 4; ++j) {
            int row = r * 16 + slot * 4 + j;
            float ssum = 0.f, ssq = 0.f;
#pragma unroll
            for (int c = 0; c < 4; ++c) { float2 e = scrA[row * 4 + c]; ssum += e.x; ssq += e.y; }
            float mean = ssum * (1.f / 192.f);
            float inv = rsqrtf(ssq * (1.f / 192.f) - mean * mean + 1e-5f);
#pragma unroll
            for (int nf = 0; nf < 3; ++nf) {
                int col = cg * 48 + l15 + nf * 16;
                tln[row * 200 + col] = f2bf((acc[nf][j] - mean) * inv * ln1_g[col] + ln1_b[col]);
            }
        }
    }
    __syncthreads();

    // ---- Ph2: q, k, v GEMMs (A = tln) ----
    const ushort* qkvT = wb + 98304;
    const ushort* aTln = tln + rowA * 200 + slot * 8;
    {
        f32x4 acc[3] = {};
        mm<3, 6>(aTln, qkvT + ((size_t)(cg * 48 + l15)) * 192 + slot * 8, 16 * 192, acc);
#pragma unroll
        for (int nf = 0; nf < 3; ++nf) {
            int col = cg * 48 + l15 + nf * 16;
            float bias = qkv_b[col];
#pragma unroll
            for (int j = 0; j < 4; ++j)
                qb[(r * 16 + slot * 4 + j) * 200 + col] = f2bf(acc[nf][j] + bias);
        }
    }
    {
        f32x4 acc[3] = {};
        mm<3, 6>(aTln, qkvT + ((size_t)(192 + cg * 48 + l15)) * 192 + slot * 8, 16 * 192, acc);
#pragma unroll
        for (int nf = 0; nf < 3; ++nf) {
            int col = cg * 48 + l15 + nf * 16;
            float bias = qkv_b[192 + col];
#pragma unroll
            for (int j = 0; j < 4; ++j)
                kb[(r * 16 + slot * 4 + j) * 200 + col] = f2bf(acc[nf][j] + bias);
        }
    }
    {
        f32x4 acc[3] = {};
        mm<3, 6>(aTln, qkvT + ((size_t)(384 + cg * 48 + l15)) * 192 + slot * 8, 16 * 192, acc);
#pragma unroll
        for (int nf = 0; nf < 3; ++nf) {
            int col = cg * 48 + l15 + nf * 16;
            float bias = qkv_b[384 + col];
            ushort4 pk;
            pk.x = f2bf(acc[nf][0] + bias); pk.y = f2bf(acc[nf][1] + bias);
            pk.z = f2bf(acc[nf][2] + bias); pk.w = f2bf(acc[nf][3] + bias);
            *reinterpret_cast<ushort4*>(&vT[col * 72 + r * 16 + slot * 4]) = pk;  // transposed
        }
    }
    __syncthreads();

    // ---- Ph5: attention, single pass, wave = (r, head=cg) ----
    const float scale = 0.14433756729740643f;  // 1/sqrt(48)
    {
        const int h = cg;
        uint4 z = make_uint4(0, 0, 0, 0);
        const ushort* qrowp = qb + rowA * 200 + h * 48;
        uint4 qa1v = *reinterpret_cast<const uint4*>(qrowp + slot * 8);
        uint4 qa2v = (slot < 2) ? *reinterpret_cast<const uint4*>(qrowp + 32 + slot * 8) : z;
        bf16x8 qaf1 = *reinterpret_cast<bf16x8*>(&qa1v);
        bf16x8 qaf2 = *reinterpret_cast<bf16x8*>(&qa2v);
        f32x4 S[4] = {};
#pragma unroll
        for (int nf = 0; nf < 4; ++nf) {
            const ushort* kp = kb + (l15 + nf * 16) * 200 + h * 48;
            uint4 kb1v = *reinterpret_cast<const uint4*>(kp + slot * 8);
            uint4 kb2v = (slot < 2) ? *reinterpret_cast<const uint4*>(kp + 32 + slot * 8) : z;
            S[nf] = __builtin_amdgcn_mfma_f32_16x16x32_bf16(qaf1, *reinterpret_cast<bf16x8*>(&kb1v), S[nf], 0, 0, 0);
            S[nf] = __builtin_amdgcn_mfma_f32_16x16x32_bf16(qaf2, *reinterpret_cast<bf16x8*>(&kb2v), S[nf], 0, 0, 0);
        }
        __syncthreads();   // all QK reads of qb/kb done before P overwrites that region
        // bias + softmax (row entirely within wave: 16 lanes x 4 nf = 64 cols) + P write
#pragma unroll
        for (int j = 0; j < 4; ++j) {
            int qrow = r * 16 + slot * 4 + j;
            int qh = qrow >> 3, qw = qrow & 7;
            float sv[4];
            float mx = -1e30f;
#pragma unroll
            for (int nf = 0; nf < 4; ++nf) {
                int krow = l15 + nf * 16;
                int idx = (qh - (krow >> 3) + 7) * 15 + (qw - (krow & 7) + 7);
                sv[nf] = S[nf][j] * scale + rpb[idx * 4 + h];
                mx = fmaxf(mx, sv[nf]);
            }
#pragma unroll
            for (int m = 1; m < 16; m <<= 1) mx = fmaxf(mx, __shfl_xor(mx, m));
            float sum = 0.f;
#pragma unroll
            for (int nf = 0; nf < 4; ++nf) { sv[nf] = expf(sv[nf] - mx); sum += sv[nf]; }
#pragma unroll
            for (int m = 1; m < 16; m <<= 1) sum += __shfl_xor(sum, m);
            float inv = 1.f / sum;
#pragma unroll
            for (int nf = 0; nf < 4; ++nf)
                P[h * 4608 + qrow * 72 + l15 + nf * 16] = f2bf(sv[nf] * inv);
        }
        __syncthreads();
        // PV: ob[rows r*16..][h*48..+48] = P @ V
        f32x4 O[3] = {};
        const ushort* prow = P + h * 4608 + rowA * 72 + slot * 8;
#pragma unroll
        for (int ki = 0; ki < 2; ++ki) {
            bf16x8 pa = *reinterpret_cast<const bf16x8*>(prow + ki * 32);
#pragma unroll
            for (int nf = 0; nf < 3; ++nf) {
                bf16x8 vb = *reinterpret_cast<const bf16x8*>(&vT[(h * 48 + l15 + nf * 16) * 72 + ki * 32 + slot * 8]);
                O[nf] = __builtin_amdgcn_mfma_f32_16x16x32_bf16(pa, vb, O[nf], 0, 0, 0);
            }
        }
#pragma unroll
        for (int nf = 0; nf < 3; ++nf)
#pragma unroll
            for (int j = 0; j < 4; ++j)
                ob[(r * 16 + slot * 4 + j) * 200 + h * 48 + l15 + nf * 16] = f2bf(O[nf][j]);
    }
    __syncthreads();

    // ---- Ph6: proj + residual + fused LN2 ----
    {
        const float alpha = alphap[0];
        f32x4 acc[3] = {};
        mm<3, 6>(ob + rowA * 200 + slot * 8,
                 wb + 208896 + ((size_t)(cg * 48 + l15)) * 192 + slot * 8, 16 * 192, acc);
        float vv[3][4];
        float s[4] = {}, s2[4] = {};
#pragma unroll
        for (int j = 0; j < 4; ++j) {
            int row = r * 16 + slot * 4 + j;
#pragma unroll
            for (int nf = 0; nf < 3; ++nf) {
                int col = cg * 48 + l15 + nf * 16;
                float v = tokg[((size_t)(b * 64 + row)) * 192 + col] + alpha * (acc[nf][j] + proj_b[col]);
                vv[nf][j] = v;
                outf[row * 196 + col] = v;
                s[j] += v; s2[j] += v * v;
            }
        }
#pragma unroll
        for (int m = 1; m < 16; m <<= 1)
#pragma unroll
            for (int j = 0; j < 4; ++j) { s[j] += __shfl_xor(s[j], m); s2[j] += __shfl_xor(s2[j], m); }
        if (l15 == 0)
#pragma unroll
            for (int j = 0; j < 4; ++j) {
                int row = r * 16 + slot * 4 + j;
                scrB[row * 4 + cg] = make_float2(s[j], s2[j]);
            }
        __syncthreads();
#pragma unroll
        for (int j = 0; j < 4; ++j) {
            int row = r * 16 + slot * 4 + j;
            float ssum = 0.f, ssq = 0.f;
#pragma unroll
            for (int c = 0; c < 4; ++c) { float2 e = scrB[row * 4 + c]; ssum += e.x; ssq += e.y; }
            float mean = ssum * (1.f / 192.f);
            float inv = rsqrtf(ssq * (1.f / 192.f) - mean * mean + 1e-5f);
#pragma unroll
            for (int nf = 0; nf < 3; ++nf) {
                int col = cg * 48 + l15 + nf * 16;
                t2[row * 200 + col] = f2bf((vv[nf][j] - mean) * inv * ln2_g[col] + ln2_b[col]);
            }
        }
    }
    __syncthreads();

    // ---- Ph7: ffn1 + exact GELU ----
    {
        f32x4 acc[6] = {};
        mm<6, 6>(t2 + rowA * 200 + slot * 8,
                 wb + 245760 + ((size_t)(cg * 96 + l15)) * 192 + slot * 8, 16 * 192, acc);
        ushort* hb = (cg < 2) ? h0 : h1;
        int cbase = (cg & 1) * 96;
#pragma unroll
        for (int nf = 0; nf < 6; ++nf) {
            int gcol = cg * 96 + nf * 16 + l15;
            int lcol = cbase + nf * 16 + l15;
            float bias = ffn_b1[gcol];
#pragma unroll
            for (int j = 0; j < 4; ++j) {
                float v = acc[nf][j] + bias;
                v = 0.5f * v * (1.f + erff(v * 0.70710678118654752f));
                hb[(r * 16 + slot * 4 + j) * 200 + lcol] = f2bf(v);
            }
        }
    }
    __syncthreads();

    // ---- Ph8: ffn2 + residual -> o2 (bf16) ----
    {
        f32x4 acc[3] = {};
        const ushort* b0 = wb + 319488 + ((size_t)(cg * 48 + l15)) * 384 + slot * 8;
        mm<3, 6>(h0 + rowA * 200 + slot * 8, b0, 16 * 384, acc);
        mm<3, 6>(h1 + rowA * 200 + slot * 8, b0 + 192, 16 * 384, acc);
#pragma unroll
        for (int nf = 0; nf < 3; ++nf) {
            int col = cg * 48 + l15 + nf * 16;
            float bias = ffn_b2[col];
#pragma unroll
            for (int j = 0; j < 4; ++j) {
                int row = r * 16 + slot * 4 + j;
                o2[row * 200 + col] = f2bf(outf[row * 196 + col] + acc[nf][j] + bias);
            }
        }
    }
    __syncthreads();

    // ---- Ph9: conv2 -> y (f32, global) ----
    {
        f32x4 acc[4] = {};
        mm<4, 6>(o2 + rowA * 200 + slot * 8,
                 wb + 49152 + ((size_t)(cg * 64 + l15)) * 192 + slot * 8, 16 * 192, acc);
#pragma unroll
        for (int nf = 0; nf < 4; ++nf) {
            int col = cg * 64 + l15 + nf * 16;
#pragma unroll
            for (int j = 0; j < 4; ++j) {
                int row = r * 16 + slot * 4 + j;
                y[((size_t)(b * 64 + row)) * 256 + col] = acc[nf][j];
            }
        }
    }
}

// ---------------- final: out[b,c,h,w] = x[b,c,h,w] + y[b,patch(h,w),c] ----------------
__global__ __launch_bounds__(256) void final_kernel(const float* __restrict__ x,
                                                    const float* __restrict__ y,
                                                    float* __restrict__ out) {
    size_t g = (size_t)blockIdx.x * 256 + threadIdx.x;  // over B*C*H*W/4
    int w4 = g & 7, hh = (g >> 3) & 31, c = (g >> 8) & 255, b = (int)(g >> 16);
    int p = (hh >> 2) * 8 + w4;
    float yv = y[((size_t)b * NP + p) * Cch + c];
    float4 xv = reinterpret_cast<const float4*>(x)[g];
    float4 ov = make_float4(xv.x + yv, xv.y + yv, xv.z + yv, xv.w + yv);
    reinterpret_cast<float4*>(out)[g] = ov;
}

extern "C" void kernel_launch(void* const* d_in, const int* in_sizes, int n_in,
                              void* d_out, int out_size, void* d_ws, size_t ws_size,
                              hipStream_t stream) {
    const float* x       = (const float*)d_in[0];
    const float* conv1_w = (const float*)d_in[1];
    const float* conv2_w = (const float*)d_in[2];
    const float* qkv_w   = (const float*)d_in[3];
    const float* qkv_b   = (const float*)d_in[4];
    const float* proj_w  = (const float*)d_in[5];
    const float* proj_b  = (const float*)d_in[6];
    const float* ffn_w1  = (const float*)d_in[7];
    const float* ffn_b1  = (const float*)d_in[8];
    const float* ffn_w2  = (const float*)d_in[9];
    const float* ffn_b2  = (const float*)d_in[10];
    const float* ln1_g   = (const float*)d_in[11];
    const float* ln1_b   = (const float*)d_in[12];
    const float* ln2_g   = (const float*)d_in[13];
    const float* ln2_b   = (const float*)d_in[14];
    const float* alpha   = (const float*)d_in[15];
    const float* rpb     = (const float*)d_in[16];
    float* out = (float*)d_out;

    // workspace layout
    float* ws_f = (float*)d_ws;
    float*  tokg = ws_f;                     // 8192*192 f32
    float*  ybuf = ws_f + 1572864;           // 8192*256 f32
    ushort* us   = (ushort*)(ws_f + 3670016);
    ushort* xm   = us;                       // 8192*256 bf16
    ushort* wb   = us + 2097152;             // 393216 bf16 weights

    // K0: weights -> bf16 (transposed to [N][K] where needed)
    wprep_kernel<<<1536, 256, 0, stream>>>(conv1_w, conv2_w, qkv_w, proj_w, ffn_w1, ffn_w2, wb);
    // K1: patch mean of x -> xm bf16 [8192,256]
    patchmean_kernel<<<8192, 256, 0, stream>>>(x, xm);
    // K2: whole token pipeline, one block per image, 16 waves
    mega_kernel<<<Bsz, 1024, 0, stream>>>(xm, wb, qkv_b, proj_b, ffn_b1, ffn_b2,
                                          ln1_g, ln1_b, ln2_g, ln2_b, alpha, rpb,
                                          tokg, ybuf);
    // K3: out = x + broadcast(y)
    final_kernel<<<(Bsz * Cch * Him * Wim) / 1024, 256, 0, stream>>>(x, ybuf, out);
}

// Round 5
// 167.469 us; speedup vs baseline: 1.8240x; 1.1037x over previous
//
#include <hip/hip_runtime.h>
#include <hip/hip_bf16.h>

// Problem dims
#define Bsz 128
#define Cch 256
#define Him 32
#define Wim 32
#define TD 192
#define NH 4
#define HD 48
#define FF 384
#define NP 64            // 8x8 patches

typedef float f32x4 __attribute__((ext_vector_type(4)));
typedef __bf16 bf16x8 __attribute__((ext_vector_type(8)));

__device__ __forceinline__ ushort f2bf(float f) {
    union { __hip_bfloat16 h; ushort u; } cv;
    cv.h = __float2bfloat16(f);
    return cv.u;
}

// ---------------- weight prep: convert (+transpose) all weights to bf16 Wt[n][k] ----------------
// layout in wb (ushort elems): c1[0,49152) c2[49152,98304) qkvT[98304,208896)
//                              projT[208896,245760) ffn1T[245760,319488) ffn2T[319488,393216)
__global__ __launch_bounds__(256) void wprep_kernel(const float* __restrict__ c1,
                                                    const float* __restrict__ c2,
                                                    const float* __restrict__ qw,
                                                    const float* __restrict__ pw,
                                                    const float* __restrict__ f1,
                                                    const float* __restrict__ f2,
                                                    ushort* __restrict__ wb) {
    int g = blockIdx.x * 256 + threadIdx.x;  // 393216 total
    float v;
    if (g < 49152) v = c1[g];                                   // conv1_w [192][256] already [N][K]
    else if (g < 98304) v = c2[g - 49152];                      // conv2_w [256][192] already [N][K]
    else if (g < 208896) { int i = g - 98304;  int n = i / 192, k = i - n * 192; v = qw[k * 576 + n]; }
    else if (g < 245760) { int i = g - 208896; int n = i / 192, k = i - n * 192; v = pw[k * 192 + n]; }
    else if (g < 319488) { int i = g - 245760; int n = i / 192, k = i - n * 192; v = f1[k * 384 + n]; }
    else                 { int i = g - 319488; int n = i / 384, k = i - n * 384; v = f2[k * 192 + n]; }
    wb[g] = f2bf(v);
}

// ---------------- bulk-load GEMM helper: issue ALL B loads, then MFMA ----------------
// A from LDS (a0 = lane row ptr + slot*8); B global (b0 = lane col ptr + slot*8).
// Covers NK = 2*H k-chunks of 32. Register cost: 2*NF*H uint4.
template <int NF, int H>
__device__ __forceinline__ void mm2(const ushort* __restrict__ a0,
                                    const ushort* __restrict__ b0,
                                    int bstride, f32x4* acc) {
    uint4 bA[NF * H], bB[NF * H];
#pragma unroll
    for (int kk = 0; kk < H; ++kk)
#pragma unroll
        for (int nf = 0; nf < NF; ++nf)
            bA[kk * NF + nf] = *reinterpret_cast<const uint4*>(b0 + (size_t)nf * bstride + kk * 32);
#pragma unroll
    for (int kk = 0; kk < H; ++kk)
#pragma unroll
        for (int nf = 0; nf < NF; ++nf)
            bB[kk * NF + nf] = *reinterpret_cast<const uint4*>(b0 + (size_t)nf * bstride + (H + kk) * 32);
#pragma unroll
    for (int kk = 0; kk < H; ++kk) {
        bf16x8 af = *reinterpret_cast<const bf16x8*>(a0 + kk * 32);
#pragma unroll
        for (int nf = 0; nf < NF; ++nf)
            acc[nf] = __builtin_amdgcn_mfma_f32_16x16x32_bf16(af, *reinterpret_cast<bf16x8*>(&bA[kk * NF + nf]), acc[nf], 0, 0, 0);
    }
#pragma unroll
    for (int kk = 0; kk < H; ++kk) {
        bf16x8 af = *reinterpret_cast<const bf16x8*>(a0 + (H + kk) * 32);
#pragma unroll
        for (int nf = 0; nf < NF; ++nf)
            acc[nf] = __builtin_amdgcn_mfma_f32_16x16x32_bf16(af, *reinterpret_cast<bf16x8*>(&bB[kk * NF + nf]), acc[nf], 0, 0, 0);
    }
}

// ---------------- mega kernel: one block per image, 8 waves, whole pipeline ----------------
// wave w: r = w>>1 (16-row group), cc = w&1 (col half / head-slot)
// LDS (131072 B):
//  [0,25600)        tln [64][200]   -> P2 [2][64][72] -> h0 [64][200] -> yl [64][258] f32 (spans to 66048)
//  [25600,51200)    qb  [64][200]   -> outf [64][196] f32 (spans to 75760)
//  [51200,76800)    kb  [64][200]   ; xm [64][266] bf16 (Ph0-Ph1, spans to 85248)
//  [76800,104448)   vT  [192][72]   -> t2 [64][200] -> o2 [64][200]
//  [104448,130048)  ob  [64][200]   -> h1 [64][200]
//  [130048,131072)  scr f32[256]
__global__ __launch_bounds__(512, 2) void mega_kernel(
    const float* __restrict__ x, const ushort* __restrict__ wb,
    const float* __restrict__ qkv_b, const float* __restrict__ proj_b,
    const float* __restrict__ ffn_b1, const float* __restrict__ ffn_b2,
    const float* __restrict__ ln1_g, const float* __restrict__ ln1_b,
    const float* __restrict__ ln2_g, const float* __restrict__ ln2_b,
    const float* __restrict__ alphap, const float* __restrict__ rpb,
    float* __restrict__ tokg, float* __restrict__ outp) {
    __shared__ __align__(16) char LDS[131072];
    ushort* tln  = (ushort*)(LDS);
    ushort* qb   = (ushort*)(LDS + 25600);
    ushort* kb   = (ushort*)(LDS + 51200);
    ushort* vT   = (ushort*)(LDS + 76800);
    ushort* ob   = (ushort*)(LDS + 104448);
    ushort* P2   = (ushort*)(LDS);
    float*  outf = (float*)(LDS + 25600);
    ushort* t2   = (ushort*)(LDS + 76800);
    ushort* h0   = (ushort*)(LDS);
    ushort* h1   = (ushort*)(LDS + 104448);
    ushort* o2   = (ushort*)(LDS + 76800);
    float*  scr  = (float*)(LDS + 130048);
    ushort* xm   = (ushort*)(LDS + 51200);   // [64][266]
    float*  yl   = (float*)(LDS);            // [64][258]

    const int b = blockIdx.x;
    const int tid = threadIdx.x, lane = tid & 63, w = tid >> 6;
    const int l15 = lane & 15, slot = lane >> 4;
    const int r = w >> 1, cc = w & 1;
    const int rowA = r * 16 + l15;
    const float alpha = alphap[0];

    // ---- Ph0: patch means of this image -> xm (LDS, bf16) ----
    for (int e = tid; e < 16384; e += 512) {
        int c = e >> 6, p = e & 63;
        int ph = p >> 3, pw = p & 7;
        const float* px = x + ((size_t)(b * Cch + c) * Him + ph * 4) * Wim + pw * 4;
        float4 s0 = *reinterpret_cast<const float4*>(px);
        float4 s1 = *reinterpret_cast<const float4*>(px + Wim);
        float4 s2 = *reinterpret_cast<const float4*>(px + 2 * Wim);
        float4 s3 = *reinterpret_cast<const float4*>(px + 3 * Wim);
        float s = s0.x + s0.y + s0.z + s0.w + s1.x + s1.y + s1.z + s1.w +
                  s2.x + s2.y + s2.z + s2.w + s3.x + s3.y + s3.z + s3.w;
        xm[p * 266 + c] = f2bf(s * 0.0625f);
    }
    __syncthreads();

    // ---- Ph1: conv1 (tokens = xm @ c1^T) + fused LN1 ----
    {
        f32x4 acc[6] = {};
        const ushort* a0 = xm + rowA * 266 + slot * 8;
        const ushort* b0 = wb + (size_t)(cc * 96 + l15) * 256 + slot * 8;
        mm2<6, 2>(a0, b0, 16 * 256, acc);
        mm2<6, 2>(a0 + 128, b0 + 128, 16 * 256, acc);
        float s[4] = {}, s2[4] = {};
#pragma unroll
        for (int nf = 0; nf < 6; ++nf)
#pragma unroll
            for (int j = 0; j < 4; ++j) {
                float v = acc[nf][j];
                int row = r * 16 + slot * 4 + j;
                int col = cc * 96 + l15 + nf * 16;
                tokg[((size_t)(b * 64 + row)) * 192 + col] = v;
                s[j] += v; s2[j] += v * v;
            }
#pragma unroll
        for (int m = 1; m < 16; m <<= 1)
#pragma unroll
            for (int j = 0; j < 4; ++j) { s[j] += __shfl_xor(s[j], m); s2[j] += __shfl_xor(s2[j], m); }
        if (l15 == 0)
#pragma unroll
            for (int j = 0; j < 4; ++j) {
                int row = r * 16 + slot * 4 + j;
                scr[row * 2 + cc] = s[j]; scr[128 + row * 2 + cc] = s2[j];
            }
        __syncthreads();
#pragma unroll
        for (int j = 0; j < 4; ++j) {
            int row = r * 16 + slot * 4 + j;
            float ssum = scr[row * 2] + scr[row * 2 + 1];
            float ssq  = scr[128 + row * 2] + scr[128 + row * 2 + 1];
            float mean = ssum * (1.f / 192.f);
            float inv = rsqrtf(ssq * (1.f / 192.f) - mean * mean + 1e-5f);
#pragma unroll
            for (int nf = 0; nf < 6; ++nf) {
                int col = cc * 96 + l15 + nf * 16;
                tln[row * 200 + col] = f2bf((acc[nf][j] - mean) * inv * ln1_g[col] + ln1_b[col]);
            }
        }
    }
    __syncthreads();

    // ---- Ph2: q, k, v GEMMs (A = tln) ----
    const ushort* qkvT = wb + 98304;
    const ushort* aTln = tln + rowA * 200 + slot * 8;
    {
        f32x4 acc[6] = {};
        mm2<6, 3>(aTln, qkvT + (size_t)(cc * 96 + l15) * 192 + slot * 8, 16 * 192, acc);
#pragma unroll
        for (int nf = 0; nf < 6; ++nf) {
            int col = cc * 96 + l15 + nf * 16;
            float bias = qkv_b[col];
#pragma unroll
            for (int j = 0; j < 4; ++j)
                qb[(r * 16 + slot * 4 + j) * 200 + col] = f2bf(acc[nf][j] + bias);
        }
    }
    {
        f32x4 acc[6] = {};
        mm2<6, 3>(aTln, qkvT + (size_t)(192 + cc * 96 + l15) * 192 + slot * 8, 16 * 192, acc);
#pragma unroll
        for (int nf = 0; nf < 6; ++nf) {
            int col = cc * 96 + l15 + nf * 16;
            float bias = qkv_b[192 + col];
#pragma unroll
            for (int j = 0; j < 4; ++j)
                kb[(r * 16 + slot * 4 + j) * 200 + col] = f2bf(acc[nf][j] + bias);
        }
    }
    {
        f32x4 acc[6] = {};
        mm2<6, 3>(aTln, qkvT + (size_t)(384 + cc * 96 + l15) * 192 + slot * 8, 16 * 192, acc);
#pragma unroll
        for (int nf = 0; nf < 6; ++nf) {
            int col = cc * 96 + l15 + nf * 16;
            float bias = qkv_b[384 + col];
            ushort4 pk;
            pk.x = f2bf(acc[nf][0] + bias); pk.y = f2bf(acc[nf][1] + bias);
            pk.z = f2bf(acc[nf][2] + bias); pk.w = f2bf(acc[nf][3] + bias);
            *reinterpret_cast<ushort4*>(&vT[col * 72 + r * 16 + slot * 4]) = pk;  // transposed
        }
    }
    __syncthreads();

    // ---- Ph5: attention, 2 passes x 2 heads (wave -> (r, head-slot cc)) ----
    const float scale = 0.14433756729740643f;  // 1/sqrt(48)
    const int hh = cc;
#pragma unroll 1
    for (int p = 0; p < 2; ++p) {
        int h = p * 2 + hh;
        if (p) __syncthreads();   // P2 reuse across passes
        // prefetch rpb biases into regs (overlaps following LDS reads / MFMAs)
        float rb[4][4];
#pragma unroll
        for (int j = 0; j < 4; ++j) {
            int qrow = r * 16 + slot * 4 + j;
            int qh = qrow >> 3, qw = qrow & 7;
#pragma unroll
            for (int nf = 0; nf < 4; ++nf) {
                int krow = l15 + nf * 16;
                rb[j][nf] = rpb[((qh - (krow >> 3) + 7) * 15 + (qw - (krow & 7) + 7)) * 4 + h];
            }
        }
        uint4 z = make_uint4(0, 0, 0, 0);
        const ushort* qrowp = qb + rowA * 200 + h * 48;
        uint4 qa1v = *reinterpret_cast<const uint4*>(qrowp + slot * 8);
        uint4 qa2v = (slot < 2) ? *reinterpret_cast<const uint4*>(qrowp + 32 + slot * 8) : z;
        bf16x8 qaf1 = *reinterpret_cast<bf16x8*>(&qa1v);
        bf16x8 qaf2 = *reinterpret_cast<bf16x8*>(&qa2v);
        f32x4 S[4] = {};
#pragma unroll
        for (int nf = 0; nf < 4; ++nf) {
            const ushort* kp = kb + (l15 + nf * 16) * 200 + h * 48;
            uint4 kb1v = *reinterpret_cast<const uint4*>(kp + slot * 8);
            uint4 kb2v = (slot < 2) ? *reinterpret_cast<const uint4*>(kp + 32 + slot * 8) : z;
            S[nf] = __builtin_amdgcn_mfma_f32_16x16x32_bf16(qaf1, *reinterpret_cast<bf16x8*>(&kb1v), S[nf], 0, 0, 0);
            S[nf] = __builtin_amdgcn_mfma_f32_16x16x32_bf16(qaf2, *reinterpret_cast<bf16x8*>(&kb2v), S[nf], 0, 0, 0);
        }
        __syncthreads();
        // bias + softmax (row within wave: 16 lanes x 4 nf) + P write
#pragma unroll
        for (int j = 0; j < 4; ++j) {
            int qrow = r * 16 + slot * 4 + j;
            float sv[4];
            float mx = -1e30f;
#pragma unroll
            for (int nf = 0; nf < 4; ++nf) {
                sv[nf] = S[nf][j] * scale + rb[j][nf];
                mx = fmaxf(mx, sv[nf]);
            }
#pragma unroll
            for (int m = 1; m < 16; m <<= 1) mx = fmaxf(mx, __shfl_xor(mx, m));
            float sum = 0.f;
#pragma unroll
            for (int nf = 0; nf < 4; ++nf) { sv[nf] = expf(sv[nf] - mx); sum += sv[nf]; }
#pragma unroll
            for (int m = 1; m < 16; m <<= 1) sum += __shfl_xor(sum, m);
            float inv = 1.f / sum;
#pragma unroll
            for (int nf = 0; nf < 4; ++nf)
                P2[hh * 4608 + qrow * 72 + l15 + nf * 16] = f2bf(sv[nf] * inv);
        }
        __syncthreads();
        // PV
        f32x4 O[3] = {};
        const ushort* prow = P2 + hh * 4608 + rowA * 72 + slot * 8;
#pragma unroll
        for (int ki = 0; ki < 2; ++ki) {
            bf16x8 pa = *reinterpret_cast<const bf16x8*>(prow + ki * 32);
#pragma unroll
            for (int nf = 0; nf < 3; ++nf) {
                bf16x8 vb = *reinterpret_cast<const bf16x8*>(&vT[(h * 48 + l15 + nf * 16) * 72 + ki * 32 + slot * 8]);
                O[nf] = __builtin_amdgcn_mfma_f32_16x16x32_bf16(pa, vb, O[nf], 0, 0, 0);
            }
        }
#pragma unroll
        for (int nf = 0; nf < 3; ++nf)
#pragma unroll
            for (int j = 0; j < 4; ++j)
                ob[(r * 16 + slot * 4 + j) * 200 + h * 48 + l15 + nf * 16] = f2bf(O[nf][j]);
    }
    __syncthreads();

    // ---- Ph6: proj + residual + fused LN2 ----
    {
        // prefetch residual (tokens) into regs
        float tr[6][4];
#pragma unroll
        for (int nf = 0; nf < 6; ++nf)
#pragma unroll
            for (int j = 0; j < 4; ++j)
                tr[nf][j] = tokg[((size_t)(b * 64 + r * 16 + slot * 4 + j)) * 192 + cc * 96 + l15 + nf * 16];
        f32x4 acc[6] = {};
        mm2<6, 3>(ob + rowA * 200 + slot * 8,
                  wb + 208896 + (size_t)(cc * 96 + l15) * 192 + slot * 8, 16 * 192, acc);
        float vv[6][4];
        float s[4] = {}, s2[4] = {};
#pragma unroll
        for (int j = 0; j < 4; ++j) {
            int row = r * 16 + slot * 4 + j;
#pragma unroll
            for (int nf = 0; nf < 6; ++nf) {
                int col = cc * 96 + l15 + nf * 16;
                float v = tr[nf][j] + alpha * (acc[nf][j] + proj_b[col]);
                vv[nf][j] = v;
                outf[row * 196 + col] = v;
                s[j] += v; s2[j] += v * v;
            }
        }
#pragma unroll
        for (int m = 1; m < 16; m <<= 1)
#pragma unroll
            for (int j = 0; j < 4; ++j) { s[j] += __shfl_xor(s[j], m); s2[j] += __shfl_xor(s2[j], m); }
        if (l15 == 0)
#pragma unroll
            for (int j = 0; j < 4; ++j) {
                int row = r * 16 + slot * 4 + j;
                scr[row * 2 + cc] = s[j]; scr[128 + row * 2 + cc] = s2[j];
            }
        __syncthreads();
#pragma unroll
        for (int j = 0; j < 4; ++j) {
            int row = r * 16 + slot * 4 + j;
            float ssum = scr[row * 2] + scr[row * 2 + 1];
            float ssq  = scr[128 + row * 2] + scr[128 + row * 2 + 1];
            float mean = ssum * (1.f / 192.f);
            float inv = rsqrtf(ssq * (1.f / 192.f) - mean * mean + 1e-5f);
#pragma unroll
            for (int nf = 0; nf < 6; ++nf) {
                int col = cc * 96 + l15 + nf * 16;
                t2[row * 200 + col] = f2bf((vv[nf][j] - mean) * inv * ln2_g[col] + ln2_b[col]);
            }
        }
    }
    __syncthreads();

    // ---- Ph7: ffn1 + exact GELU -> h0/h1 ----
    {
        f32x4 acc[12] = {};
        const ushort* aT = t2 + rowA * 200 + slot * 8;
        mm2<6, 3>(aT, wb + 245760 + (size_t)(cc * 192 + l15) * 192 + slot * 8, 16 * 192, acc);
        mm2<6, 3>(aT, wb + 245760 + (size_t)(cc * 192 + 96 + l15) * 192 + slot * 8, 16 * 192, acc + 6);
        ushort* hb = cc ? h1 : h0;
#pragma unroll
        for (int q2 = 0; q2 < 2; ++q2)
#pragma unroll
            for (int nf = 0; nf < 6; ++nf) {
                int lcol = q2 * 96 + nf * 16 + l15;
                float bias = ffn_b1[cc * 192 + lcol];
#pragma unroll
                for (int j = 0; j < 4; ++j) {
                    float v = acc[q2 * 6 + nf][j] + bias;
                    v = 0.5f * v * (1.f + erff(v * 0.70710678118654752f));
                    hb[(r * 16 + slot * 4 + j) * 200 + lcol] = f2bf(v);
                }
            }
    }
    __syncthreads();

    // ---- Ph8: ffn2 + residual -> o2 (bf16) ----
    {
        f32x4 acc[6] = {};
        const ushort* b0 = wb + 319488 + (size_t)(cc * 96 + l15) * 384 + slot * 8;
        mm2<6, 3>(h0 + rowA * 200 + slot * 8, b0, 16 * 384, acc);
        mm2<6, 3>(h1 + rowA * 200 + slot * 8, b0 + 192, 16 * 384, acc);
#pragma unroll
        for (int nf = 0; nf < 6; ++nf) {
            int col = cc * 96 + l15 + nf * 16;
            float bias = ffn_b2[col];
#pragma unroll
            for (int j = 0; j < 4; ++j) {
                int row = r * 16 + slot * 4 + j;
                o2[row * 200 + col] = f2bf(outf[row * 196 + col] + acc[nf][j] + bias);
            }
        }
    }
    __syncthreads();

    // ---- Ph9: conv2 -> yl (LDS, f32) ----
    {
        f32x4 acc[8] = {};
        const ushort* aO = o2 + rowA * 200 + slot * 8;
        mm2<4, 3>(aO, wb + 49152 + (size_t)(cc * 128 + l15) * 192 + slot * 8, 16 * 192, acc);
        mm2<4, 3>(aO, wb + 49152 + (size_t)(cc * 128 + 64 + l15) * 192 + slot * 8, 16 * 192, acc + 4);
#pragma unroll
        for (int q2 = 0; q2 < 2; ++q2)
#pragma unroll
            for (int nf = 0; nf < 4; ++nf) {
                int col = cc * 128 + q2 * 64 + nf * 16 + l15;
#pragma unroll
                for (int j = 0; j < 4; ++j)
                    yl[(r * 16 + slot * 4 + j) * 258 + col] = acc[q2 * 4 + nf][j];
            }
    }
    __syncthreads();

    // ---- Ph10: out[b,c,h,w] = x + broadcast(yl) ----
    {
        const float4* x4 = reinterpret_cast<const float4*>(x) + (size_t)b * 65536;
        float4* o4 = reinterpret_cast<float4*>(outp) + (size_t)b * 65536;
        for (int i = tid; i < 65536; i += 512) {
            int c = i >> 8, rem = i & 255;
            int hh2 = rem >> 3, w4 = rem & 7;
            int p = (hh2 >> 2) * 8 + w4;
            float yv = yl[p * 258 + c];
            float4 xv = x4[i];
            o4[i] = make_float4(xv.x + yv, xv.y + yv, xv.z + yv, xv.w + yv);
        }
    }
}

extern "C" void kernel_launch(void* const* d_in, const int* in_sizes, int n_in,
                              void* d_out, int out_size, void* d_ws, size_t ws_size,
                              hipStream_t stream) {
    const float* x       = (const float*)d_in[0];
    const float* conv1_w = (const float*)d_in[1];
    const float* conv2_w = (const float*)d_in[2];
    const float* qkv_w   = (const float*)d_in[3];
    const float* qkv_b   = (const float*)d_in[4];
    const float* proj_w  = (const float*)d_in[5];
    const float* proj_b  = (const float*)d_in[6];
    const float* ffn_w1  = (const float*)d_in[7];
    const float* ffn_b1  = (const float*)d_in[8];
    const float* ffn_w2  = (const float*)d_in[9];
    const float* ffn_b2  = (const float*)d_in[10];
    const float* ln1_g   = (const float*)d_in[11];
    const float* ln1_b   = (const float*)d_in[12];
    const float* ln2_g   = (const float*)d_in[13];
    const float* ln2_b   = (const float*)d_in[14];
    const float* alpha   = (const float*)d_in[15];
    const float* rpb     = (const float*)d_in[16];
    float* out = (float*)d_out;

    // workspace
    float* ws_f = (float*)d_ws;
    float*  tokg = ws_f;                      // 8192*192 f32
    ushort* wb   = (ushort*)(ws_f + 1572864); // 393216 bf16 weights

    // K0: weights -> bf16 (transposed to [N][K] where needed)
    wprep_kernel<<<1536, 256, 0, stream>>>(conv1_w, conv2_w, qkv_w, proj_w, ffn_w1, ffn_w2, wb);
    // K1: full pipeline, one block per image
    mega_kernel<<<Bsz, 512, 0, stream>>>(x, wb, qkv_b, proj_b, ffn_b1, ffn_b2,
                                         ln1_g, ln1_b, ln2_g, ln2_b, alpha, rpb,
                                         tokg, out);
}

// Round 6
// 130.273 us; speedup vs baseline: 2.3448x; 1.2855x over previous
//
#include <hip/hip_runtime.h>
#include <hip/hip_bf16.h>

// Problem dims
#define Bsz 128
#define Cch 256
#define Him 32
#define Wim 32
#define TD 192
#define NH 4
#define HD 48
#define FF 384
#define NP 64

typedef float f32x4 __attribute__((ext_vector_type(4)));
typedef __bf16 bf16x8 __attribute__((ext_vector_type(8)));
typedef unsigned int u32;

#define MFMA(a, b, c) __builtin_amdgcn_mfma_f32_16x16x32_bf16(a, b, c, 0, 0, 0)
#define LD8(p) (*reinterpret_cast<const bf16x8*>(p))
#define WAITV asm volatile("s_waitcnt vmcnt(0)" ::: "memory")

__device__ __forceinline__ ushort f2bf(float f) {
    union { __hip_bfloat16 h; ushort u; } cv;
    cv.h = __float2bfloat16(f);
    return cv.u;
}

__device__ __forceinline__ void gload16(const void* g, void* l) {
    __builtin_amdgcn_global_load_lds((const __attribute__((address_space(1))) u32*)g,
                                     (__attribute__((address_space(3))) u32*)l, 16, 0, 0);
}

// stage a 32-col weight chunk into LDS, linear dest + inverse-swizzled global source.
// LDS logical layout: byte(col,kb) = col*K2B + (kb ^ ((col&7)<<4))
template <int K2B>
__device__ __forceinline__ void stageW(char* lbuf, const char* g0, int colStrB, int tid) {
    constexpr int CHB = 32 * K2B;
    constexpr int NR = (CHB + 8191) / 8192;
#pragma unroll
    for (int rd = 0; rd < NR; ++rd) {
        int p = rd * 8192 + tid * 16;
        if (p < CHB) {
            int col = p / K2B;
            int kb = (p - col * K2B) ^ ((col & 7) << 4);
            gload16(g0 + (size_t)col * colStrB + kb, lbuf + p);
        }
    }
}

// ---------------- weight prep: bf16 Wt[n][k] ----------------
// wb (ushort): c1[0,49152) c2[49152,98304) qkvT[98304,208896)
//              projT[208896,245760) ffn1T[245760,319488) ffn2T[319488,393216)
__global__ __launch_bounds__(256) void wprep_kernel(const float* __restrict__ c1,
                                                    const float* __restrict__ c2,
                                                    const float* __restrict__ qw,
                                                    const float* __restrict__ pw,
                                                    const float* __restrict__ f1,
                                                    const float* __restrict__ f2,
                                                    ushort* __restrict__ wb) {
    int g = blockIdx.x * 256 + threadIdx.x;
    float v;
    if (g < 49152) v = c1[g];
    else if (g < 98304) v = c2[g - 49152];
    else if (g < 208896) { int i = g - 98304;  int n = i / 192, k = i - n * 192; v = qw[k * 576 + n]; }
    else if (g < 245760) { int i = g - 208896; int n = i / 192, k = i - n * 192; v = pw[k * 192 + n]; }
    else if (g < 319488) { int i = g - 245760; int n = i / 192, k = i - n * 192; v = f1[k * 384 + n]; }
    else                 { int i = g - 319488; int n = i / 384, k = i - n * 384; v = f2[k * 192 + n]; }
    wb[g] = f2bf(v);
}

// ---------------- patch mean -> xm bf16 [8192][256] ----------------
__global__ __launch_bounds__(256) void patchmean_kernel(const float* __restrict__ x,
                                                        ushort* __restrict__ xm) {
    int g = blockIdx.x * 256 + threadIdx.x;
    int nw = g & 7, nh = (g >> 3) & 7, c = (g >> 6) & 255, b = g >> 14;
    const float* px = x + ((size_t)(b * Cch + c) * Him + nh * 4) * Wim + nw * 4;
    float4 s0 = *reinterpret_cast<const float4*>(px);
    float4 s1 = *reinterpret_cast<const float4*>(px + Wim);
    float4 s2 = *reinterpret_cast<const float4*>(px + 2 * Wim);
    float4 s3 = *reinterpret_cast<const float4*>(px + 3 * Wim);
    float s = s0.x + s0.y + s0.z + s0.w + s1.x + s1.y + s1.z + s1.w +
              s2.x + s2.y + s2.z + s2.w + s3.x + s3.y + s3.z + s3.w;
    xm[(size_t)(b * NP + nh * 8 + nw) * Cch + c] = f2bf(s * 0.0625f);
}

// ---------------- token kernel: one block per image, 8 waves ----------------
// LDS (130048 B):
//  [0,25600)       tln [64][200]   ; P2 pass0 ; t2 later
//  [25600,51200)   qb              ; ob later ; h0
//  [51200,76800)   kb              ; h1
//  [76800,104448)  vT [192][72]    ; o2 later
//  [104448,129024) stage 2x12288   ; P2 pass1
//  [129024,130048) scr float2[128]
__global__ __launch_bounds__(512, 2) void token_kernel(
    const ushort* __restrict__ xm, const ushort* __restrict__ wb,
    const float* __restrict__ qkv_b, const float* __restrict__ proj_b,
    const float* __restrict__ ffn_b1, const float* __restrict__ ffn_b2,
    const float* __restrict__ ln1_g, const float* __restrict__ ln1_b,
    const float* __restrict__ ln2_g, const float* __restrict__ ln2_b,
    const float* __restrict__ alphap, const float* __restrict__ rpb,
    float* __restrict__ y) {
    __shared__ __align__(16) char LDS[130048];
    ushort* tln = (ushort*)(LDS);
    ushort* qb  = (ushort*)(LDS + 25600);
    ushort* kb  = (ushort*)(LDS + 51200);
    ushort* vT  = (ushort*)(LDS + 76800);
    char*   SBB = LDS + 104448;
    float2* scr2 = (float2*)(LDS + 129024);
    ushort* t2  = tln;
    ushort* obp = qb;
    ushort* h0  = qb;
    ushort* h1  = kb;
    ushort* o2  = vT;
#define SBUF(i) (SBB + (i) * 12288)

    const int b = blockIdx.x;
    const int tid = threadIdx.x, lane = tid & 63, w = tid >> 6;
    const int l15 = lane & 15, slot = lane >> 4, slot16 = slot * 16;
    const int r = w >> 1, cc = w & 1;
    const int rowA = r * 16 + l15;
    const int orow = r * 16 + slot * 4;
    const int xp = (l15 & 7) << 4;
    const int colB = cc * 16 + l15;          // col within 32-col chunk

    f32x4 tok[6];                            // tokens (residual 1), persists to proj
    f32x4 pj[6];                             // proj out (residual 2), persists to ffn2
#pragma unroll
    for (int c = 0; c < 6; ++c) { tok[c] = f32x4{0,0,0,0}; pj[c] = f32x4{0,0,0,0}; }

    // ================ Ph1: conv1 + LN1 ================
    {
        const char* xrow = (const char*)xm + ((size_t)(b * 64 + rowA)) * 512;
        bf16x8 a1[2][4];
#pragma unroll
        for (int kh = 0; kh < 2; ++kh)
#pragma unroll
            for (int ks = 0; ks < 4; ++ks)
                a1[kh][ks] = LD8(xrow + kh * 256 + ks * 64 + slot16);
        const char* c1g = (const char*)wb;
        stageW<256>(SBUF(0), c1g, 512, tid);
#pragma unroll
        for (int j = 0; j < 12; ++j) {
            WAITV; __syncthreads();
            if (j < 11) {
                int jn = j + 1;
                stageW<256>(SBUF(jn & 1), c1g + (size_t)(jn >> 1) * (32 * 512) + (jn & 1) * 256, 512, tid);
            }
            const char* bp = SBUF(j & 1) + colB * 256;
            int c = j >> 1, kh = j & 1;
#pragma unroll
            for (int ks = 0; ks < 4; ++ks) {
                int kbx = (ks * 64 + slot16) ^ xp;
                tok[c] = MFMA(a1[kh][ks], LD8(bp + kbx), tok[c]);
            }
        }
        stageW<384>(SBUF(0), (const char*)(wb + 98304), 384, tid);  // qkv j0
        // LN1
        float s[4] = {}, s2[4] = {};
#pragma unroll
        for (int c = 0; c < 6; ++c)
#pragma unroll
            for (int j2 = 0; j2 < 4; ++j2) { float v = tok[c][j2]; s[j2] += v; s2[j2] += v * v; }
#pragma unroll
        for (int m = 1; m < 16; m <<= 1)
#pragma unroll
            for (int j2 = 0; j2 < 4; ++j2) { s[j2] += __shfl_xor(s[j2], m); s2[j2] += __shfl_xor(s2[j2], m); }
        if (l15 == 0)
#pragma unroll
            for (int j2 = 0; j2 < 4; ++j2) scr2[(orow + j2) * 2 + cc] = make_float2(s[j2], s2[j2]);
        __syncthreads();
#pragma unroll
        for (int j2 = 0; j2 < 4; ++j2) {
            int row = orow + j2;
            float2 eA = scr2[row * 2], eB = scr2[row * 2 + 1];
            float mean = (eA.x + eB.x) * (1.f / 192.f);
            float inv = rsqrtf((eA.y + eB.y) * (1.f / 192.f) - mean * mean + 1e-5f);
#pragma unroll
            for (int c = 0; c < 6; ++c) {
                int col = c * 32 + colB;
                tln[row * 200 + col] = f2bf((tok[c][j2] - mean) * inv * ln1_g[col] + ln1_b[col]);
            }
        }
    }

    // ================ Ph2: qkv (18 chunk-jobs) ================
    {
        WAITV; __syncthreads();
        bf16x8 aT[6];
        const char* trow = (const char*)tln + rowA * 400;
#pragma unroll
        for (int ks = 0; ks < 6; ++ks) aT[ks] = LD8(trow + ks * 64 + slot16);
        const char* qg = (const char*)(wb + 98304);
#pragma unroll
        for (int j = 0; j < 18; ++j) {
            if (j) { WAITV; __syncthreads(); }
            if (j < 17) stageW<384>(SBUF((j + 1) & 1), qg + (size_t)(j + 1) * (32 * 384), 384, tid);
            const char* bp = SBUF(j & 1) + colB * 384;
            f32x4 acc = f32x4{0,0,0,0};
#pragma unroll
            for (int ks = 0; ks < 6; ++ks) {
                int kbx = (ks * 64 + slot16) ^ xp;
                acc = MFMA(aT[ks], LD8(bp + kbx), acc);
            }
            int col = (j % 6) * 32 + colB;
            if (j < 6) {
                float bias = qkv_b[col];
#pragma unroll
                for (int j2 = 0; j2 < 4; ++j2) qb[(orow + j2) * 200 + col] = f2bf(acc[j2] + bias);
            } else if (j < 12) {
                float bias = qkv_b[192 + col];
#pragma unroll
                for (int j2 = 0; j2 < 4; ++j2) kb[(orow + j2) * 200 + col] = f2bf(acc[j2] + bias);
            } else {
                float bias = qkv_b[384 + col];
                ushort4 pk;
                pk.x = f2bf(acc[0] + bias); pk.y = f2bf(acc[1] + bias);
                pk.z = f2bf(acc[2] + bias); pk.w = f2bf(acc[3] + bias);
                *reinterpret_cast<ushort4*>(&vT[col * 72 + orow]) = pk;  // transposed
            }
        }
    }
    __syncthreads();

    // ================ Ph3: attention ================
    {
        const float scale = 0.14433756729740643f;  // 1/sqrt(48)
        ushort* P2b0 = (ushort*)(LDS + cc * 9216);            // heads 0,1
        ushort* P2b1 = (ushort*)(LDS + 104448 + cc * 9216);   // heads 2,3
#pragma unroll
        for (int p = 0; p < 2; ++p) {
            int h = p * 2 + cc;
            ushort* P2 = p ? P2b1 : P2b0;
            float rb[4][4];
#pragma unroll
            for (int j2 = 0; j2 < 4; ++j2) {
                int qrow = orow + j2, qh = qrow >> 3, qw = qrow & 7;
#pragma unroll
                for (int nf = 0; nf < 4; ++nf) {
                    int krow = l15 + nf * 16;
                    rb[j2][nf] = rpb[((qh - (krow >> 3) + 7) * 15 + (qw - (krow & 7) + 7)) * 4 + h];
                }
            }
            uint4 z = make_uint4(0, 0, 0, 0);
            const char* qrp = (const char*)qb + rowA * 400 + h * 96;
            uint4 qa1 = *(const uint4*)(qrp + slot16);
            uint4 qa2 = (slot < 2) ? *(const uint4*)(qrp + 64 + slot16) : z;
            f32x4 S[4] = {};
#pragma unroll
            for (int nf = 0; nf < 4; ++nf) {
                const char* kp = (const char*)kb + (l15 + nf * 16) * 400 + h * 96;
                uint4 k1 = *(const uint4*)(kp + slot16);
                uint4 k2 = (slot < 2) ? *(const uint4*)(kp + 64 + slot16) : z;
                S[nf] = MFMA(*(bf16x8*)&qa1, *(bf16x8*)&k1, S[nf]);
                S[nf] = MFMA(*(bf16x8*)&qa2, *(bf16x8*)&k2, S[nf]);
            }
#pragma unroll
            for (int j2 = 0; j2 < 4; ++j2) {
                float sv[4]; float mx = -1e30f;
#pragma unroll
                for (int nf = 0; nf < 4; ++nf) { sv[nf] = S[nf][j2] * scale + rb[j2][nf]; mx = fmaxf(mx, sv[nf]); }
#pragma unroll
                for (int m = 1; m < 16; m <<= 1) mx = fmaxf(mx, __shfl_xor(mx, m));
                float sum = 0.f;
#pragma unroll
                for (int nf = 0; nf < 4; ++nf) { sv[nf] = expf(sv[nf] - mx); sum += sv[nf]; }
#pragma unroll
                for (int m = 1; m < 16; m <<= 1) sum += __shfl_xor(sum, m);
                float inv = 1.f / sum;
                int qrow = orow + j2;
#pragma unroll
                for (int nf = 0; nf < 4; ++nf) P2[qrow * 72 + l15 + nf * 16] = f2bf(sv[nf] * inv);
            }
        }
        __syncthreads();   // all qb/kb reads done
#pragma unroll
        for (int p = 0; p < 2; ++p) {
            int h = p * 2 + cc;
            ushort* P2 = p ? P2b1 : P2b0;
            f32x4 O[3] = {};
            const char* prow = (const char*)P2 + rowA * 144;
#pragma unroll
            for (int ki = 0; ki < 2; ++ki) {
                bf16x8 pa = LD8(prow + ki * 64 + slot16);
#pragma unroll
                for (int nf = 0; nf < 3; ++nf) {
                    bf16x8 vb = LD8((const char*)vT + (h * 48 + l15 + nf * 16) * 144 + ki * 64 + slot16);
                    O[nf] = MFMA(pa, vb, O[nf]);
                }
            }
#pragma unroll
            for (int nf = 0; nf < 3; ++nf)
#pragma unroll
                for (int j2 = 0; j2 < 4; ++j2)
                    obp[(orow + j2) * 200 + h * 48 + l15 + nf * 16] = f2bf(O[nf][j2]);
        }
        __syncthreads();   // all P2 reads done -> staging region reusable
        stageW<384>(SBUF(0), (const char*)(wb + 208896), 384, tid);  // proj j0
    }

    // ================ Ph4: proj + residual + LN2 ================
    {
        WAITV; __syncthreads();
        bf16x8 aO[6];
        const char* orw = (const char*)obp + rowA * 400;
#pragma unroll
        for (int ks = 0; ks < 6; ++ks) aO[ks] = LD8(orw + ks * 64 + slot16);
        const char* pg = (const char*)(wb + 208896);
#pragma unroll
        for (int j = 0; j < 6; ++j) {
            if (j) { WAITV; __syncthreads(); }
            if (j < 5) stageW<384>(SBUF((j + 1) & 1), pg + (size_t)(j + 1) * (32 * 384), 384, tid);
            const char* bp = SBUF(j & 1) + colB * 384;
#pragma unroll
            for (int ks = 0; ks < 6; ++ks) {
                int kbx = (ks * 64 + slot16) ^ xp;
                pj[j] = MFMA(aO[ks], LD8(bp + kbx), pj[j]);
            }
        }
        stageW<384>(SBUF(0), (const char*)(wb + 245760), 384, tid);  // ffn1 j0
        const float alpha = alphap[0];
        float s[4] = {}, s2[4] = {};
#pragma unroll
        for (int c = 0; c < 6; ++c) {
            int col = c * 32 + colB;
            float pb = proj_b[col];
#pragma unroll
            for (int j2 = 0; j2 < 4; ++j2) {
                float v = tok[c][j2] + alpha * (pj[c][j2] + pb);
                pj[c][j2] = v;
                s[j2] += v; s2[j2] += v * v;
            }
        }
#pragma unroll
        for (int m = 1; m < 16; m <<= 1)
#pragma unroll
            for (int j2 = 0; j2 < 4; ++j2) { s[j2] += __shfl_xor(s[j2], m); s2[j2] += __shfl_xor(s2[j2], m); }
        if (l15 == 0)
#pragma unroll
            for (int j2 = 0; j2 < 4; ++j2) scr2[(orow + j2) * 2 + cc] = make_float2(s[j2], s2[j2]);
        __syncthreads();
#pragma unroll
        for (int j2 = 0; j2 < 4; ++j2) {
            int row = orow + j2;
            float2 eA = scr2[row * 2], eB = scr2[row * 2 + 1];
            float mean = (eA.x + eB.x) * (1.f / 192.f);
            float inv = rsqrtf((eA.y + eB.y) * (1.f / 192.f) - mean * mean + 1e-5f);
#pragma unroll
            for (int c = 0; c < 6; ++c) {
                int col = c * 32 + colB;
                t2[row * 200 + col] = f2bf((pj[c][j2] - mean) * inv * ln2_g[col] + ln2_b[col]);
            }
        }
    }

    // ================ Ph5: ffn1 + GELU (12 jobs) ================
    {
        WAITV; __syncthreads();
        bf16x8 aT2[6];
        const char* trow = (const char*)t2 + rowA * 400;
#pragma unroll
        for (int ks = 0; ks < 6; ++ks) aT2[ks] = LD8(trow + ks * 64 + slot16);
        const char* fg = (const char*)(wb + 245760);
#pragma unroll
        for (int j = 0; j < 12; ++j) {
            if (j) { WAITV; __syncthreads(); }
            if (j < 11) stageW<384>(SBUF((j + 1) & 1), fg + (size_t)(j + 1) * (32 * 384), 384, tid);
            const char* bp = SBUF(j & 1) + colB * 384;
            f32x4 acc = f32x4{0,0,0,0};
#pragma unroll
            for (int ks = 0; ks < 6; ++ks) {
                int kbx = (ks * 64 + slot16) ^ xp;
                acc = MFMA(aT2[ks], LD8(bp + kbx), acc);
            }
            int col384 = j * 32 + colB;
            float bias = ffn_b1[col384];
            ushort* hb = (j < 6) ? h0 : h1;
            int lcol = (j < 6) ? col384 : col384 - 192;
#pragma unroll
            for (int j2 = 0; j2 < 4; ++j2) {
                float v = acc[j2] + bias;
                v = 0.5f * v * (1.f + erff(v * 0.70710678118654752f));
                hb[(orow + j2) * 200 + lcol] = f2bf(v);
            }
        }
        stageW<384>(SBUF(0), (const char*)(wb + 319488), 768, tid);  // ffn2 j0 (c=0,kh=0)
    }

    // ================ Ph6: ffn2 + residual (12 jobs) ================
    {
        WAITV; __syncthreads();
        bf16x8 ah[2][6];
        const char* h0r = (const char*)h0 + rowA * 400;
        const char* h1r = (const char*)h1 + rowA * 400;
#pragma unroll
        for (int ks = 0; ks < 6; ++ks) {
            ah[0][ks] = LD8(h0r + ks * 64 + slot16);
            ah[1][ks] = LD8(h1r + ks * 64 + slot16);
        }
        const char* f2g = (const char*)(wb + 319488);
        f32x4 f2a[6];
#pragma unroll
        for (int c = 0; c < 6; ++c) f2a[c] = f32x4{0,0,0,0};
#pragma unroll
        for (int j = 0; j < 12; ++j) {
            if (j) { WAITV; __syncthreads(); }
            if (j < 11) {
                int jn = j + 1;
                stageW<384>(SBUF(jn & 1), f2g + (size_t)(jn >> 1) * (32 * 768) + (jn & 1) * 384, 768, tid);
            }
            const char* bp = SBUF(j & 1) + colB * 384;
            int c = j >> 1, kh = j & 1;
#pragma unroll
            for (int ks = 0; ks < 6; ++ks) {
                int kbx = (ks * 64 + slot16) ^ xp;
                f2a[c] = MFMA(ah[kh][ks], LD8(bp + kbx), f2a[c]);
            }
        }
        stageW<384>(SBUF(0), (const char*)(wb + 49152), 384, tid);  // conv2 j0
#pragma unroll
        for (int c = 0; c < 6; ++c) {
            int col = c * 32 + colB;
            float bias = ffn_b2[col];
#pragma unroll
            for (int j2 = 0; j2 < 4; ++j2)
                o2[(orow + j2) * 200 + col] = f2bf(pj[c][j2] + f2a[c][j2] + bias);
        }
    }

    // ================ Ph7: conv2 -> y (8 jobs) ================
    {
        WAITV; __syncthreads();
        bf16x8 aO2[6];
        const char* o2r = (const char*)o2 + rowA * 400;
#pragma unroll
        for (int ks = 0; ks < 6; ++ks) aO2[ks] = LD8(o2r + ks * 64 + slot16);
        const char* c2g = (const char*)(wb + 49152);
        float* yb = y + (size_t)b * 64 * 256;
#pragma unroll
        for (int j = 0; j < 8; ++j) {
            if (j) { WAITV; __syncthreads(); }
            if (j < 7) stageW<384>(SBUF((j + 1) & 1), c2g + (size_t)(j + 1) * (32 * 384), 384, tid);
            const char* bp = SBUF(j & 1) + colB * 384;
            f32x4 acc = f32x4{0,0,0,0};
#pragma unroll
            for (int ks = 0; ks < 6; ++ks) {
                int kbx = (ks * 64 + slot16) ^ xp;
                acc = MFMA(aO2[ks], LD8(bp + kbx), acc);
            }
            int col = j * 32 + colB;
#pragma unroll
            for (int j2 = 0; j2 < 4; ++j2)
                yb[(size_t)(orow + j2) * 256 + col] = acc[j2];
        }
    }
#undef SBUF
}

// ---------------- final: out = x + broadcast(y) ----------------
__global__ __launch_bounds__(256) void final_kernel(const float* __restrict__ x,
                                                    const float* __restrict__ y,
                                                    float* __restrict__ out) {
    size_t g = (size_t)blockIdx.x * 256 + threadIdx.x;
    int w4 = g & 7, hh = (g >> 3) & 31, c = (g >> 8) & 255, b = (int)(g >> 16);
    int p = (hh >> 2) * 8 + w4;
    float yv = y[((size_t)b * NP + p) * Cch + c];
    float4 xv = reinterpret_cast<const float4*>(x)[g];
    reinterpret_cast<float4*>(out)[g] = make_float4(xv.x + yv, xv.y + yv, xv.z + yv, xv.w + yv);
}

extern "C" void kernel_launch(void* const* d_in, const int* in_sizes, int n_in,
                              void* d_out, int out_size, void* d_ws, size_t ws_size,
                              hipStream_t stream) {
    const float* x       = (const float*)d_in[0];
    const float* conv1_w = (const float*)d_in[1];
    const float* conv2_w = (const float*)d_in[2];
    const float* qkv_w   = (const float*)d_in[3];
    const float* qkv_b   = (const float*)d_in[4];
    const float* proj_w  = (const float*)d_in[5];
    const float* proj_b  = (const float*)d_in[6];
    const float* ffn_w1  = (const float*)d_in[7];
    const float* ffn_b1  = (const float*)d_in[8];
    const float* ffn_w2  = (const float*)d_in[9];
    const float* ffn_b2  = (const float*)d_in[10];
    const float* ln1_g   = (const float*)d_in[11];
    const float* ln1_b   = (const float*)d_in[12];
    const float* ln2_g   = (const float*)d_in[13];
    const float* ln2_b   = (const float*)d_in[14];
    const float* alpha   = (const float*)d_in[15];
    const float* rpb     = (const float*)d_in[16];
    float* out = (float*)d_out;

    float* ws_f = (float*)d_ws;
    float*  ybuf = ws_f;                          // 8192*256 f32
    ushort* xm   = (ushort*)(ws_f + 2097152);     // 8192*256 bf16
    ushort* wb   = xm + 2097152;                  // 393216 bf16 weights

    wprep_kernel<<<1536, 256, 0, stream>>>(conv1_w, conv2_w, qkv_w, proj_w, ffn_w1, ffn_w2, wb);
    patchmean_kernel<<<8192, 256, 0, stream>>>(x, xm);
    token_kernel<<<Bsz, 512, 0, stream>>>(xm, wb, qkv_b, proj_b, ffn_b1, ffn_b2,
                                          ln1_g, ln1_b, ln2_g, ln2_b, alpha, rpb, ybuf);
    final_kernel<<<(Bsz * Cch * Him * Wim) / 1024, 256, 0, stream>>>(x, ybuf, out);
}

// Round 7
// 114.998 us; speedup vs baseline: 2.6563x; 1.1328x over previous
//
#include <hip/hip_runtime.h>
#include <hip/hip_bf16.h>

// Problem dims
#define Bsz 128
#define Cch 256
#define Him 32
#define Wim 32
#define TD 192
#define NH 4
#define HD 48
#define FF 384
#define NP 64

typedef float f32x4 __attribute__((ext_vector_type(4)));
typedef __bf16 bf16x8 __attribute__((ext_vector_type(8)));
typedef unsigned int u32;

#define MFMA(a, b, c) __builtin_amdgcn_mfma_f32_16x16x32_bf16(a, b, c, 0, 0, 0)
#define LD8(p) (*reinterpret_cast<const bf16x8*>(p))
#define VM0 asm volatile("s_waitcnt vmcnt(0)" ::: "memory")
#define VM2 asm volatile("s_waitcnt vmcnt(2)" ::: "memory")
#define VMB do { if (wlow) { asm volatile("s_waitcnt vmcnt(4)" ::: "memory"); } \
                 else      { asm volatile("s_waitcnt vmcnt(2)" ::: "memory"); } } while (0)
#define LGKM0 asm volatile("s_waitcnt lgkmcnt(0)" ::: "memory")
#define SBAR __builtin_amdgcn_s_barrier()

__device__ __forceinline__ ushort f2bf(float f) {
    union { __hip_bfloat16 h; ushort u; } cv;
    cv.h = __float2bfloat16(f);
    return cv.u;
}

__device__ __forceinline__ void gload16(const void* g, void* l) {
    __builtin_amdgcn_global_load_lds((const __attribute__((address_space(1))) u32*)g,
                                     (__attribute__((address_space(3))) u32*)l, 16, 0, 0);
}

// stage a 32-col weight chunk into LDS, linear dest + inverse-swizzled global source.
// LDS logical layout: byte(col,kb) = col*K2B + (kb ^ ((col&7)<<4))
template <int K2B>
__device__ __forceinline__ void stageW(char* lbuf, const char* g0, int colStrB, int tid) {
    constexpr int CHB = 32 * K2B;
    constexpr int NR = (CHB + 8191) / 8192;
#pragma unroll
    for (int rd = 0; rd < NR; ++rd) {
        int p = rd * 8192 + tid * 16;
        if (p < CHB) {
            int col = p / K2B;
            int kb = (p - col * K2B) ^ ((col & 7) << 4);
            gload16(g0 + (size_t)col * colStrB + kb, lbuf + p);
        }
    }
}

// ---------------- weight prep: bf16 Wt[n][k] ----------------
// wb (ushort): c1[0,49152) c2[49152,98304) qkvT[98304,208896)
//              projT[208896,245760) ffn1T[245760,319488) ffn2T[319488,393216)
__global__ __launch_bounds__(256) void wprep_kernel(const float* __restrict__ c1,
                                                    const float* __restrict__ c2,
                                                    const float* __restrict__ qw,
                                                    const float* __restrict__ pw,
                                                    const float* __restrict__ f1,
                                                    const float* __restrict__ f2,
                                                    ushort* __restrict__ wb) {
    int g = blockIdx.x * 256 + threadIdx.x;
    float v;
    if (g < 49152) v = c1[g];
    else if (g < 98304) v = c2[g - 49152];
    else if (g < 208896) { int i = g - 98304;  int n = i / 192, k = i - n * 192; v = qw[k * 576 + n]; }
    else if (g < 245760) { int i = g - 208896; int n = i / 192, k = i - n * 192; v = pw[k * 192 + n]; }
    else if (g < 319488) { int i = g - 245760; int n = i / 192, k = i - n * 192; v = f1[k * 384 + n]; }
    else                 { int i = g - 319488; int n = i / 384, k = i - n * 384; v = f2[k * 192 + n]; }
    wb[g] = f2bf(v);
}

// ---------------- patch mean -> xm bf16 [8192][256] ----------------
__global__ __launch_bounds__(256) void patchmean_kernel(const float* __restrict__ x,
                                                        ushort* __restrict__ xm) {
    int g = blockIdx.x * 256 + threadIdx.x;
    int nw = g & 7, nh = (g >> 3) & 7, c = (g >> 6) & 255, b = g >> 14;
    const float* px = x + ((size_t)(b * Cch + c) * Him + nh * 4) * Wim + nw * 4;
    float4 s0 = *reinterpret_cast<const float4*>(px);
    float4 s1 = *reinterpret_cast<const float4*>(px + Wim);
    float4 s2 = *reinterpret_cast<const float4*>(px + 2 * Wim);
    float4 s3 = *reinterpret_cast<const float4*>(px + 3 * Wim);
    float s = s0.x + s0.y + s0.z + s0.w + s1.x + s1.y + s1.z + s1.w +
              s2.x + s2.y + s2.z + s2.w + s3.x + s3.y + s3.z + s3.w;
    xm[(size_t)(b * NP + nh * 8 + nw) * Cch + c] = f2bf(s * 0.0625f);
}

// ---------------- token kernel: one block per image, 8 waves, 4-deep staging ----------------
// LDS (154624 B):
//  [0,25600)        tln [64][200]   ; P2 pass0 ; t2 later
//  [25600,51200)    qb              ; ob later ; h0
//  [51200,76800)    kb              ; h1
//  [76800,104448)   vT [192][72]    ; o2 later
//  [104448,153600)  stage 4x12288   ; P2 pass1 in [104448,122880) during attn
//  [153600,154624)  scr float2[128]
__global__ __launch_bounds__(512, 1) void token_kernel(
    const ushort* __restrict__ xm, const ushort* __restrict__ wb,
    const float* __restrict__ qkv_b, const float* __restrict__ proj_b,
    const float* __restrict__ ffn_b1, const float* __restrict__ ffn_b2,
    const float* __restrict__ ln1_g, const float* __restrict__ ln1_b,
    const float* __restrict__ ln2_g, const float* __restrict__ ln2_b,
    const float* __restrict__ alphap, const float* __restrict__ rpb,
    ushort* __restrict__ y) {
    __shared__ __align__(16) char LDS[154624];
    ushort* tln = (ushort*)(LDS);
    ushort* qb  = (ushort*)(LDS + 25600);
    ushort* kb  = (ushort*)(LDS + 51200);
    ushort* vT  = (ushort*)(LDS + 76800);
    char*   SBB = LDS + 104448;
    float2* scr2 = (float2*)(LDS + 153600);
    ushort* t2  = tln;
    ushort* obp = qb;
    ushort* h0  = qb;
    ushort* h1  = kb;
    ushort* o2  = vT;
#define SBUF(i) (SBB + (i) * 12288)

    const int b = blockIdx.x;
    const int tid = threadIdx.x, lane = tid & 63, w = tid >> 6;
    const int l15 = lane & 15, slot = lane >> 4, slot16 = slot * 16;
    const int r = w >> 1, cc = w & 1;
    const int rowA = r * 16 + l15;
    const int orow = r * 16 + slot * 4;
    const int xp = (l15 & 7) << 4;
    const int colB = cc * 16 + l15;
    const bool wlow = (w < 4);

    // ---- preload all per-lane bias/LN constants into regs (keeps job-loop vmem clean) ----
    float qbr[18], f1br[12], l1gr[6], l1br[6], l2gr[6], l2br[6], pbr[6], f2br[6];
#pragma unroll
    for (int j = 0; j < 18; ++j) qbr[j] = qkv_b[(j / 6) * 192 + (j % 6) * 32 + colB];
#pragma unroll
    for (int j = 0; j < 12; ++j) f1br[j] = ffn_b1[j * 32 + colB];
#pragma unroll
    for (int c = 0; c < 6; ++c) {
        int col = c * 32 + colB;
        l1gr[c] = ln1_g[col]; l1br[c] = ln1_b[col];
        l2gr[c] = ln2_g[col]; l2br[c] = ln2_b[col];
        pbr[c] = proj_b[col]; f2br[c] = ffn_b2[col];
    }
    const float alpha = alphap[0];

    // A-frags for conv1 (from xm, global)
    const char* xrow = (const char*)xm + ((size_t)(b * 64 + rowA)) * 512;
    bf16x8 a1[2][4];
#pragma unroll
    for (int kh = 0; kh < 2; ++kh)
#pragma unroll
        for (int ks = 0; ks < 4; ++ks)
            a1[kh][ks] = LD8(xrow + kh * 256 + ks * 64 + slot16);

    const char* c1g = (const char*)wb;
    const char* qg  = (const char*)(wb + 98304);
    const char* pg  = (const char*)(wb + 208896);
    const char* fg  = (const char*)(wb + 245760);
    const char* f2g = (const char*)(wb + 319488);
    const char* c2g = (const char*)(wb + 49152);

    f32x4 tok[6], pj[6];
#pragma unroll
    for (int c = 0; c < 6; ++c) { tok[c] = f32x4{0,0,0,0}; pj[c] = f32x4{0,0,0,0}; }

    // ================ Ph1: conv1 (12 jobs, pattern A: 1 load/wave/job) ================
    stageW<256>(SBUF(0), c1g, 512, tid);
    stageW<256>(SBUF(1), c1g + 256, 512, tid);
    stageW<256>(SBUF(2), c1g + 16384, 512, tid);
#pragma unroll
    for (int j = 0; j < 12; ++j) {
        if (j < 10) VM2; else VM0;
        SBAR;
        if (j < 9) {
            int jn = j + 3;
            stageW<256>(SBUF(jn & 3), c1g + (size_t)(jn >> 1) * 16384 + (jn & 1) * 256, 512, tid);
        }
        const char* bp = SBUF(j & 3) + colB * 256;
        int c = j >> 1, kh = j & 1;
#pragma unroll
        for (int ks = 0; ks < 4; ++ks)
            tok[c] = MFMA(a1[kh][ks], LD8(bp + ((ks * 64 + slot16) ^ xp)), tok[c]);
    }
    // prefetch qkv j0-2 (SBUF0-2 provably free: all waves passed barriers j9-j11)
    stageW<384>(SBUF(0), qg, 384, tid);
    stageW<384>(SBUF(1), qg + 12288, 384, tid);
    stageW<384>(SBUF(2), qg + 24576, 384, tid);
    // ---- LN1 (no vmem drains: lgkm-only barriers keep qkv stages in flight) ----
    {
        float s[4] = {}, s2[4] = {};
#pragma unroll
        for (int c = 0; c < 6; ++c)
#pragma unroll
            for (int j2 = 0; j2 < 4; ++j2) { float v = tok[c][j2]; s[j2] += v; s2[j2] += v * v; }
#pragma unroll
        for (int m = 1; m < 16; m <<= 1)
#pragma unroll
            for (int j2 = 0; j2 < 4; ++j2) { s[j2] += __shfl_xor(s[j2], m); s2[j2] += __shfl_xor(s2[j2], m); }
        if (l15 == 0)
#pragma unroll
            for (int j2 = 0; j2 < 4; ++j2) scr2[(orow + j2) * 2 + cc] = make_float2(s[j2], s2[j2]);
        LGKM0; SBAR;
#pragma unroll
        for (int j2 = 0; j2 < 4; ++j2) {
            int row = orow + j2;
            float2 eA = scr2[row * 2], eB = scr2[row * 2 + 1];
            float mean = (eA.x + eB.x) * (1.f / 192.f);
            float inv = rsqrtf((eA.y + eB.y) * (1.f / 192.f) - mean * mean + 1e-5f);
#pragma unroll
            for (int c = 0; c < 6; ++c)
                tln[row * 200 + c * 32 + colB] = f2bf((tok[c][j2] - mean) * inv * l1gr[c] + l1br[c]);
        }
        LGKM0; SBAR;
    }

    // ================ Ph2: qkv (18 jobs, pattern B) ================
    {
        bf16x8 aT[6];
        const char* trow = (const char*)tln + rowA * 400;
#pragma unroll
        for (int ks = 0; ks < 6; ++ks) aT[ks] = LD8(trow + ks * 64 + slot16);
#pragma unroll
        for (int j = 0; j < 18; ++j) {
            if (j < 16) VMB; else VM0;
            SBAR;
            if (j < 15) stageW<384>(SBUF((j + 3) & 3), qg + (size_t)(j + 3) * 12288, 384, tid);
            const char* bp = SBUF(j & 3) + colB * 384;
            f32x4 acc = f32x4{0,0,0,0};
#pragma unroll
            for (int ks = 0; ks < 6; ++ks)
                acc = MFMA(aT[ks], LD8(bp + ((ks * 64 + slot16) ^ xp)), acc);
            int col = (j % 6) * 32 + colB;
            float bias = qbr[j];
            if (j < 6) {
#pragma unroll
                for (int j2 = 0; j2 < 4; ++j2) qb[(orow + j2) * 200 + col] = f2bf(acc[j2] + bias);
            } else if (j < 12) {
#pragma unroll
                for (int j2 = 0; j2 < 4; ++j2) kb[(orow + j2) * 200 + col] = f2bf(acc[j2] + bias);
            } else {
                ushort4 pk;
                pk.x = f2bf(acc[0] + bias); pk.y = f2bf(acc[1] + bias);
                pk.z = f2bf(acc[2] + bias); pk.w = f2bf(acc[3] + bias);
                *reinterpret_cast<ushort4*>(&vT[col * 72 + orow]) = pk;  // transposed
            }
        }
    }
    LGKM0; SBAR;

    // ================ Ph3: attention ================
    {
        const float scale = 0.14433756729740643f;  // 1/sqrt(48)
        ushort* P2b0 = (ushort*)(LDS + cc * 9216);            // heads 0,1 (tln region, dead)
        ushort* P2b1 = (ushort*)(LDS + 104448 + cc * 9216);   // heads 2,3 (stage region, idle)
#pragma unroll
        for (int p = 0; p < 2; ++p) {
            int h = p * 2 + cc;
            ushort* P2 = p ? P2b1 : P2b0;
            float rb[4][4];
#pragma unroll
            for (int j2 = 0; j2 < 4; ++j2) {
                int qrow = orow + j2, qh = qrow >> 3, qw = qrow & 7;
#pragma unroll
                for (int nf = 0; nf < 4; ++nf) {
                    int krow = l15 + nf * 16;
                    rb[j2][nf] = rpb[((qh - (krow >> 3) + 7) * 15 + (qw - (krow & 7) + 7)) * 4 + h];
                }
            }
            uint4 z = make_uint4(0, 0, 0, 0);
            const char* qrp = (const char*)qb + rowA * 400 + h * 96;
            uint4 qa1 = *(const uint4*)(qrp + slot16);
            uint4 qa2 = (slot < 2) ? *(const uint4*)(qrp + 64 + slot16) : z;
            f32x4 S[4] = {};
#pragma unroll
            for (int nf = 0; nf < 4; ++nf) {
                const char* kp = (const char*)kb + (l15 + nf * 16) * 400 + h * 96;
                uint4 k1 = *(const uint4*)(kp + slot16);
                uint4 k2 = (slot < 2) ? *(const uint4*)(kp + 64 + slot16) : z;
                S[nf] = MFMA(*(bf16x8*)&qa1, *(bf16x8*)&k1, S[nf]);
                S[nf] = MFMA(*(bf16x8*)&qa2, *(bf16x8*)&k2, S[nf]);
            }
#pragma unroll
            for (int j2 = 0; j2 < 4; ++j2) {
                float sv[4]; float mx = -1e30f;
#pragma unroll
                for (int nf = 0; nf < 4; ++nf) { sv[nf] = S[nf][j2] * scale + rb[j2][nf]; mx = fmaxf(mx, sv[nf]); }
#pragma unroll
                for (int m = 1; m < 16; m <<= 1) mx = fmaxf(mx, __shfl_xor(mx, m));
                float sum = 0.f;
#pragma unroll
                for (int nf = 0; nf < 4; ++nf) { sv[nf] = expf(sv[nf] - mx); sum += sv[nf]; }
#pragma unroll
                for (int m = 1; m < 16; m <<= 1) sum += __shfl_xor(sum, m);
                float inv = 1.f / sum;
                int qrow = orow + j2;
#pragma unroll
                for (int nf = 0; nf < 4; ++nf) P2[qrow * 72 + l15 + nf * 16] = f2bf(sv[nf] * inv);
            }
        }
        LGKM0; SBAR;   // all qb/kb reads done before ob (qb region) writes
#pragma unroll
        for (int p = 0; p < 2; ++p) {
            int h = p * 2 + cc;
            ushort* P2 = p ? P2b1 : P2b0;
            f32x4 O[3] = {};
            const char* prow = (const char*)P2 + rowA * 144;
#pragma unroll
            for (int ki = 0; ki < 2; ++ki) {
                bf16x8 pa = LD8(prow + ki * 64 + slot16);
#pragma unroll
                for (int nf = 0; nf < 3; ++nf) {
                    bf16x8 vb = LD8((const char*)vT + (h * 48 + l15 + nf * 16) * 144 + ki * 64 + slot16);
                    O[nf] = MFMA(pa, vb, O[nf]);
                }
            }
#pragma unroll
            for (int nf = 0; nf < 3; ++nf)
#pragma unroll
                for (int j2 = 0; j2 < 4; ++j2)
                    obp[(orow + j2) * 200 + h * 48 + l15 + nf * 16] = f2bf(O[nf][j2]);
        }
        LGKM0; SBAR;   // ob visible; P2b1 reads done -> stage region reusable
    }
    stageW<384>(SBUF(0), pg, 384, tid);
    stageW<384>(SBUF(1), pg + 12288, 384, tid);
    stageW<384>(SBUF(2), pg + 24576, 384, tid);

    // ================ Ph4: proj (6 jobs) ================
    {
        bf16x8 aO[6];
        const char* orw = (const char*)obp + rowA * 400;
#pragma unroll
        for (int ks = 0; ks < 6; ++ks) aO[ks] = LD8(orw + ks * 64 + slot16);
#pragma unroll
        for (int j = 0; j < 6; ++j) {
            if (j < 4) VMB; else VM0;
            SBAR;
            if (j < 3) stageW<384>(SBUF((j + 3) & 3), pg + (size_t)(j + 3) * 12288, 384, tid);
            const char* bp = SBUF(j & 3) + colB * 384;
#pragma unroll
            for (int ks = 0; ks < 6; ++ks)
                pj[j] = MFMA(aO[ks], LD8(bp + ((ks * 64 + slot16) ^ xp)), pj[j]);
        }
    }
    SBAR;   // all waves past proj j5 (SBUF1) before ffn1 j1 stages into SBUF1
    stageW<384>(SBUF(0), fg, 384, tid);
    stageW<384>(SBUF(1), fg + 12288, 384, tid);
    stageW<384>(SBUF(2), fg + 24576, 384, tid);
    // ---- residual + LN2 ----
    {
        float s[4] = {}, s2[4] = {};
#pragma unroll
        for (int c = 0; c < 6; ++c)
#pragma unroll
            for (int j2 = 0; j2 < 4; ++j2) {
                float v = tok[c][j2] + alpha * (pj[c][j2] + pbr[c]);
                pj[c][j2] = v;
                s[j2] += v; s2[j2] += v * v;
            }
#pragma unroll
        for (int m = 1; m < 16; m <<= 1)
#pragma unroll
            for (int j2 = 0; j2 < 4; ++j2) { s[j2] += __shfl_xor(s[j2], m); s2[j2] += __shfl_xor(s2[j2], m); }
        if (l15 == 0)
#pragma unroll
            for (int j2 = 0; j2 < 4; ++j2) scr2[(orow + j2) * 2 + cc] = make_float2(s[j2], s2[j2]);
        LGKM0; SBAR;
#pragma unroll
        for (int j2 = 0; j2 < 4; ++j2) {
            int row = orow + j2;
            float2 eA = scr2[row * 2], eB = scr2[row * 2 + 1];
            float mean = (eA.x + eB.x) * (1.f / 192.f);
            float inv = rsqrtf((eA.y + eB.y) * (1.f / 192.f) - mean * mean + 1e-5f);
#pragma unroll
            for (int c = 0; c < 6; ++c)
                t2[row * 200 + c * 32 + colB] = f2bf((pj[c][j2] - mean) * inv * l2gr[c] + l2br[c]);
        }
        LGKM0; SBAR;
    }

    // ================ Ph5: ffn1 + GELU (12 jobs) ================
    {
        bf16x8 aT2[6];
        const char* trow = (const char*)t2 + rowA * 400;
#pragma unroll
        for (int ks = 0; ks < 6; ++ks) aT2[ks] = LD8(trow + ks * 64 + slot16);
#pragma unroll
        for (int j = 0; j < 12; ++j) {
            if (j < 10) VMB; else VM0;
            SBAR;
            if (j < 9) stageW<384>(SBUF((j + 3) & 3), fg + (size_t)(j + 3) * 12288, 384, tid);
            const char* bp = SBUF(j & 3) + colB * 384;
            f32x4 acc = f32x4{0,0,0,0};
#pragma unroll
            for (int ks = 0; ks < 6; ++ks)
                acc = MFMA(aT2[ks], LD8(bp + ((ks * 64 + slot16) ^ xp)), acc);
            int col384 = j * 32 + colB;
            ushort* hb = (j < 6) ? h0 : h1;
            int lcol = (j < 6) ? col384 : col384 - 192;
#pragma unroll
            for (int j2 = 0; j2 < 4; ++j2) {
                float v = acc[j2] + f1br[j];
                v = 0.5f * v * (1.f + erff(v * 0.70710678118654752f));
                hb[(orow + j2) * 200 + lcol] = f2bf(v);
            }
        }
    }
    LGKM0; SBAR;   // h0/h1 visible; all waves past loop
    stageW<384>(SBUF(0), f2g, 768, tid);
    stageW<384>(SBUF(1), f2g + 384, 768, tid);
    stageW<384>(SBUF(2), f2g + 24576, 768, tid);

    // ================ Ph6: ffn2 (12 jobs) ================
    f32x4 f2a[6];
#pragma unroll
    for (int c = 0; c < 6; ++c) f2a[c] = f32x4{0,0,0,0};
    {
        bf16x8 ah[2][6];
        const char* h0r = (const char*)h0 + rowA * 400;
        const char* h1r = (const char*)h1 + rowA * 400;
#pragma unroll
        for (int ks = 0; ks < 6; ++ks) {
            ah[0][ks] = LD8(h0r + ks * 64 + slot16);
            ah[1][ks] = LD8(h1r + ks * 64 + slot16);
        }
#pragma unroll
        for (int j = 0; j < 12; ++j) {
            if (j < 10) VMB; else VM0;
            SBAR;
            if (j < 9) {
                int jn = j + 3;
                stageW<384>(SBUF(jn & 3), f2g + (size_t)(jn >> 1) * 24576 + (jn & 1) * 384, 768, tid);
            }
            const char* bp = SBUF(j & 3) + colB * 384;
            int c = j >> 1, kh = j & 1;
#pragma unroll
            for (int ks = 0; ks < 6; ++ks)
                f2a[c] = MFMA(ah[kh][ks], LD8(bp + ((ks * 64 + slot16) ^ xp)), f2a[c]);
        }
    }
    // SBUF0-2 free (barriers j9-j11 passed); stage conv2 j0-2, then o2 epilogue
    stageW<384>(SBUF(0), c2g, 384, tid);
    stageW<384>(SBUF(1), c2g + 12288, 384, tid);
    stageW<384>(SBUF(2), c2g + 24576, 384, tid);
#pragma unroll
    for (int c = 0; c < 6; ++c) {
        int col = c * 32 + colB;
#pragma unroll
        for (int j2 = 0; j2 < 4; ++j2)
            o2[(orow + j2) * 200 + col] = f2bf(pj[c][j2] + f2a[c][j2] + f2br[c]);
    }
    LGKM0; SBAR;

    // ================ Ph7: conv2 -> y bf16 (8 jobs) ================
    {
        bf16x8 aO2[6];
        const char* o2r = (const char*)o2 + rowA * 400;
#pragma unroll
        for (int ks = 0; ks < 6; ++ks) aO2[ks] = LD8(o2r + ks * 64 + slot16);
        ushort* yb = y + (size_t)b * 64 * 256;
#pragma unroll
        for (int j = 0; j < 8; ++j) {
            if (j < 6) VMB; else VM0;
            SBAR;
            if (j < 5) stageW<384>(SBUF((j + 3) & 3), c2g + (size_t)(j + 3) * 12288, 384, tid);
            const char* bp = SBUF(j & 3) + colB * 384;
            f32x4 acc = f32x4{0,0,0,0};
#pragma unroll
            for (int ks = 0; ks < 6; ++ks)
                acc = MFMA(aO2[ks], LD8(bp + ((ks * 64 + slot16) ^ xp)), acc);
            int col = j * 32 + colB;
#pragma unroll
            for (int j2 = 0; j2 < 4; ++j2)
                yb[(size_t)(orow + j2) * 256 + col] = f2bf(acc[j2]);
        }
    }
#undef SBUF
}

// ---------------- final: out = x + broadcast(y bf16) ----------------
__global__ __launch_bounds__(256) void final_kernel(const float* __restrict__ x,
                                                    const ushort* __restrict__ y,
                                                    float* __restrict__ out) {
    size_t g = (size_t)blockIdx.x * 256 + threadIdx.x;
    int w4 = g & 7, hh = (g >> 3) & 31, c = (g >> 8) & 255, b = (int)(g >> 16);
    int p = (hh >> 2) * 8 + w4;
    u32 yu = y[((size_t)b * NP + p) * Cch + c];
    union { u32 u; float f; } cv; cv.u = yu << 16;
    float yv = cv.f;
    float4 xv = reinterpret_cast<const float4*>(x)[g];
    reinterpret_cast<float4*>(out)[g] = make_float4(xv.x + yv, xv.y + yv, xv.z + yv, xv.w + yv);
}

extern "C" void kernel_launch(void* const* d_in, const int* in_sizes, int n_in,
                              void* d_out, int out_size, void* d_ws, size_t ws_size,
                              hipStream_t stream) {
    const float* x       = (const float*)d_in[0];
    const float* conv1_w = (const float*)d_in[1];
    const float* conv2_w = (const float*)d_in[2];
    const float* qkv_w   = (const float*)d_in[3];
    const float* qkv_b   = (const float*)d_in[4];
    const float* proj_w  = (const float*)d_in[5];
    const float* proj_b  = (const float*)d_in[6];
    const float* ffn_w1  = (const float*)d_in[7];
    const float* ffn_b1  = (const float*)d_in[8];
    const float* ffn_w2  = (const float*)d_in[9];
    const float* ffn_b2  = (const float*)d_in[10];
    const float* ln1_g   = (const float*)d_in[11];
    const float* ln1_b   = (const float*)d_in[12];
    const float* ln2_g   = (const float*)d_in[13];
    const float* ln2_b   = (const float*)d_in[14];
    const float* alpha   = (const float*)d_in[15];
    const float* rpb     = (const float*)d_in[16];
    float* out = (float*)d_out;

    ushort* ybuf = (ushort*)d_ws;                 // 8192*256 bf16
    ushort* xm   = ybuf + 2097152;                // 8192*256 bf16
    ushort* wb   = xm + 2097152;                  // 393216 bf16 weights

    wprep_kernel<<<1536, 256, 0, stream>>>(conv1_w, conv2_w, qkv_w, proj_w, ffn_w1, ffn_w2, wb);
    patchmean_kernel<<<8192, 256, 0, stream>>>(x, xm);
    token_kernel<<<Bsz, 512, 0, stream>>>(xm, wb, qkv_b, proj_b, ffn_b1, ffn_b2,
                                          ln1_g, ln1_b, ln2_g, ln2_b, alpha, rpb, ybuf);
    final_kernel<<<(Bsz * Cch * Him * Wim) / 1024, 256, 0, stream>>>(x, ybuf, out);
}

// Round 9
// 111.230 us; speedup vs baseline: 2.7463x; 1.0339x over previous
//
#include <hip/hip_runtime.h>
#include <hip/hip_bf16.h>

// Problem dims
#define Bsz 128
#define Cch 256
#define Him 32
#define Wim 32
#define TD 192
#define NH 4
#define HD 48
#define FF 384
#define NP 64

typedef float f32x4 __attribute__((ext_vector_type(4)));
typedef __bf16 bf16x8 __attribute__((ext_vector_type(8)));
typedef unsigned int u32;

#define MFMA(a, b, c) __builtin_amdgcn_mfma_f32_16x16x32_bf16(a, b, c, 0, 0, 0)
#define LD8(p) (*reinterpret_cast<const bf16x8*>(p))
#define VM0 asm volatile("s_waitcnt vmcnt(0)" ::: "memory")
#define VM2 asm volatile("s_waitcnt vmcnt(2)" ::: "memory")
#define VMB do { if (wlow) { asm volatile("s_waitcnt vmcnt(4)" ::: "memory"); } \
                 else      { asm volatile("s_waitcnt vmcnt(2)" ::: "memory"); } } while (0)
#define LGKM0 asm volatile("s_waitcnt lgkmcnt(0)" ::: "memory")
#define SBAR __builtin_amdgcn_s_barrier()

__device__ __forceinline__ ushort f2bf(float f) {
    union { __hip_bfloat16 h; ushort u; } cv;
    cv.h = __float2bfloat16(f);
    return cv.u;
}

__device__ __forceinline__ void gload16(const void* g, void* l) {
    __builtin_amdgcn_global_load_lds((const __attribute__((address_space(1))) u32*)g,
                                     (__attribute__((address_space(3))) u32*)l, 16, 0, 0);
}

// stage a 32-col weight chunk into LDS, linear dest + inverse-swizzled global source.
// LDS logical layout: byte(col,kb) = col*K2B + (kb ^ ((col&7)<<4))
template <int K2B>
__device__ __forceinline__ void stageW(char* lbuf, const char* g0, int colStrB, int tid) {
    constexpr int CHB = 32 * K2B;
    constexpr int NR = (CHB + 8191) / 8192;
#pragma unroll
    for (int rd = 0; rd < NR; ++rd) {
        int p = rd * 8192 + tid * 16;
        if (p < CHB) {
            int col = p / K2B;
            int kb = (p - col * K2B) ^ ((col & 7) << 4);
            gload16(g0 + (size_t)col * colStrB + kb, lbuf + p);
        }
    }
}

// ---------------- prep kernel: wprep (blocks 0..1535) + patch-mean (blocks 1536..2559) ----------------
// wb (ushort): c1[0,49152) c2[49152,98304) qkvT[98304,208896)
//              projT[208896,245760) ffn1T[245760,319488) ffn2T[319488,393216)
typedef ushort ushort8v __attribute__((ext_vector_type(8)));
__global__ __launch_bounds__(256) void prep_kernel(const float* __restrict__ x,
                                                   const float* __restrict__ c1,
                                                   const float* __restrict__ c2,
                                                   const float* __restrict__ qw,
                                                   const float* __restrict__ pw,
                                                   const float* __restrict__ f1,
                                                   const float* __restrict__ f2,
                                                   ushort* __restrict__ wb,
                                                   ushort* __restrict__ xm) {
    const int bb = blockIdx.x;
    const int tid = threadIdx.x;
    if (bb < 1536) {   // ---- weight convert/transpose ----
        int g = bb * 256 + tid;
        float v;
        if (g < 49152) v = c1[g];
        else if (g < 98304) v = c2[g - 49152];
        else if (g < 208896) { int i = g - 98304;  int n = i / 192, k = i - n * 192; v = qw[k * 576 + n]; }
        else if (g < 245760) { int i = g - 208896; int n = i / 192, k = i - n * 192; v = pw[k * 192 + n]; }
        else if (g < 319488) { int i = g - 245760; int n = i / 192, k = i - n * 192; v = f1[k * 384 + n]; }
        else                 { int i = g - 319488; int n = i / 384, k = i - n * 384; v = f2[k * 192 + n]; }
        wb[g] = f2bf(v);
        return;
    }
    // ---- patch mean: block = (image b, 32-channel group cg) ----
    __shared__ float acc[32][65];
    int pb = bb - 1536;            // 0..1023
    int b = pb >> 3, cg = pb & 7;
    int c = tid >> 3, wq = tid & 7;
    const float* pl = x + ((size_t)(b * Cch + cg * 32 + c) * 1024) + wq * 4;
#pragma unroll 1
    for (int nh = 0; nh < 8; ++nh) {
        const float* p0 = pl + nh * 128;
        float4 v0 = *reinterpret_cast<const float4*>(p0);
        float4 v1 = *reinterpret_cast<const float4*>(p0 + 32);
        float4 v2 = *reinterpret_cast<const float4*>(p0 + 64);
        float4 v3 = *reinterpret_cast<const float4*>(p0 + 96);
        float s = v0.x + v0.y + v0.z + v0.w + v1.x + v1.y + v1.z + v1.w +
                  v2.x + v2.y + v2.z + v2.w + v3.x + v3.y + v3.z + v3.w;
        acc[c][nh * 8 + wq] = s * 0.0625f;
    }
    __syncthreads();
    // pack + coalesced write: thread -> (p = tid>>2, c8 = (tid&3)*8)
    int p = tid >> 2, c8 = (tid & 3) * 8;
    ushort8v o;
#pragma unroll
    for (int k = 0; k < 8; ++k) o[k] = f2bf(acc[c8 + k][p]);
    *reinterpret_cast<ushort8v*>(xm + ((size_t)(b * 64 + p)) * 256 + cg * 32 + c8) = o;
}

// ---------------- token kernel: one block per image, 8 waves, 4-deep staging ----------------
// LDS (154624 B):
//  [0,25600)        tln [64][200]   ; P2 pass0 ; t2 later
//  [25600,51200)    qb              ; ob later ; h0
//  [51200,76800)    kb              ; h1
//  [76800,104448)   vT [192][72]    ; o2 later
//  [104448,153600)  stage 4x12288   ; P2 pass1 in [104448,122880) during attn
//  [153600,154624)  scr float2[128]
__global__ __launch_bounds__(512, 1) void token_kernel(
    const ushort* __restrict__ xm, const ushort* __restrict__ wb,
    const float* __restrict__ qkv_b, const float* __restrict__ proj_b,
    const float* __restrict__ ffn_b1, const float* __restrict__ ffn_b2,
    const float* __restrict__ ln1_g, const float* __restrict__ ln1_b,
    const float* __restrict__ ln2_g, const float* __restrict__ ln2_b,
    const float* __restrict__ alphap, const float* __restrict__ rpb,
    ushort* __restrict__ y) {
    __shared__ __align__(16) char LDS[154624];
    ushort* tln = (ushort*)(LDS);
    ushort* qb  = (ushort*)(LDS + 25600);
    ushort* kb  = (ushort*)(LDS + 51200);
    ushort* vT  = (ushort*)(LDS + 76800);
    char*   SBB = LDS + 104448;
    float2* scr2 = (float2*)(LDS + 153600);
    ushort* t2  = tln;
    ushort* obp = qb;
    ushort* h0  = qb;
    ushort* h1  = kb;
    ushort* o2  = vT;
#define SBUF(i) (SBB + (i) * 12288)

    const int b = blockIdx.x;
    const int tid = threadIdx.x, lane = tid & 63, w = tid >> 6;
    const int l15 = lane & 15, slot = lane >> 4, slot16 = slot * 16;
    const int r = w >> 1, cc = w & 1;
    const int rowA = r * 16 + l15;
    const int orow = r * 16 + slot * 4;
    const int xp = (l15 & 7) << 4;
    const int colB = cc * 16 + l15;
    const bool wlow = (w < 4);

    // ---- preload all per-lane bias/LN constants into regs ----
    float qbr[18], f1br[12], l1gr[6], l1br[6], l2gr[6], l2br[6], pbr[6], f2br[6];
#pragma unroll
    for (int j = 0; j < 18; ++j) qbr[j] = qkv_b[(j / 6) * 192 + (j % 6) * 32 + colB];
#pragma unroll
    for (int j = 0; j < 12; ++j) f1br[j] = ffn_b1[j * 32 + colB];
#pragma unroll
    for (int c = 0; c < 6; ++c) {
        int col = c * 32 + colB;
        l1gr[c] = ln1_g[col]; l1br[c] = ln1_b[col];
        l2gr[c] = ln2_g[col]; l2br[c] = ln2_b[col];
        pbr[c] = proj_b[col]; f2br[c] = ffn_b2[col];
    }
    const float alpha = alphap[0];

    // A-frags for conv1 (from xm, global)
    const char* xrow = (const char*)xm + ((size_t)(b * 64 + rowA)) * 512;
    bf16x8 a1[2][4];
#pragma unroll
    for (int kh = 0; kh < 2; ++kh)
#pragma unroll
        for (int ks = 0; ks < 4; ++ks)
            a1[kh][ks] = LD8(xrow + kh * 256 + ks * 64 + slot16);

    const char* c1g = (const char*)wb;
    const char* qg  = (const char*)(wb + 98304);
    const char* pg  = (const char*)(wb + 208896);
    const char* fg  = (const char*)(wb + 245760);
    const char* f2g = (const char*)(wb + 319488);
    const char* c2g = (const char*)(wb + 49152);

    f32x4 tok[6], pj[6];
#pragma unroll
    for (int c = 0; c < 6; ++c) { tok[c] = f32x4{0,0,0,0}; pj[c] = f32x4{0,0,0,0}; }

    // ================ Ph1: conv1 (12 jobs) ================
    stageW<256>(SBUF(0), c1g, 512, tid);
    stageW<256>(SBUF(1), c1g + 256, 512, tid);
    stageW<256>(SBUF(2), c1g + 16384, 512, tid);
#pragma unroll
    for (int j = 0; j < 12; ++j) {
        if (j < 10) VM2; else VM0;
        SBAR;
        if (j < 9) {
            int jn = j + 3;
            stageW<256>(SBUF(jn & 3), c1g + (size_t)(jn >> 1) * 16384 + (jn & 1) * 256, 512, tid);
        }
        const char* bp = SBUF(j & 3) + colB * 256;
        int c = j >> 1, kh = j & 1;
#pragma unroll
        for (int ks = 0; ks < 4; ++ks)
            tok[c] = MFMA(a1[kh][ks], LD8(bp + ((ks * 64 + slot16) ^ xp)), tok[c]);
    }
    // prefetch qkv j0-2
    stageW<384>(SBUF(0), qg, 384, tid);
    stageW<384>(SBUF(1), qg + 12288, 384, tid);
    stageW<384>(SBUF(2), qg + 24576, 384, tid);
    // ---- LN1 ----
    {
        float s[4] = {}, s2[4] = {};
#pragma unroll
        for (int c = 0; c < 6; ++c)
#pragma unroll
            for (int j2 = 0; j2 < 4; ++j2) { float v = tok[c][j2]; s[j2] += v; s2[j2] += v * v; }
#pragma unroll
        for (int m = 1; m < 16; m <<= 1)
#pragma unroll
            for (int j2 = 0; j2 < 4; ++j2) { s[j2] += __shfl_xor(s[j2], m); s2[j2] += __shfl_xor(s2[j2], m); }
        if (l15 == 0)
#pragma unroll
            for (int j2 = 0; j2 < 4; ++j2) scr2[(orow + j2) * 2 + cc] = make_float2(s[j2], s2[j2]);
        LGKM0; SBAR;
#pragma unroll
        for (int j2 = 0; j2 < 4; ++j2) {
            int row = orow + j2;
            float2 eA = scr2[row * 2], eB = scr2[row * 2 + 1];
            float mean = (eA.x + eB.x) * (1.f / 192.f);
            float inv = rsqrtf((eA.y + eB.y) * (1.f / 192.f) - mean * mean + 1e-5f);
#pragma unroll
            for (int c = 0; c < 6; ++c)
                tln[row * 200 + c * 32 + colB] = f2bf((tok[c][j2] - mean) * inv * l1gr[c] + l1br[c]);
        }
        LGKM0; SBAR;
    }

    // ================ Ph2: qkv (18 jobs) ================
    {
        bf16x8 aT[6];
        const char* trow = (const char*)tln + rowA * 400;
#pragma unroll
        for (int ks = 0; ks < 6; ++ks) aT[ks] = LD8(trow + ks * 64 + slot16);
#pragma unroll
        for (int j = 0; j < 18; ++j) {
            if (j < 16) VMB; else VM0;
            SBAR;
            if (j < 15) stageW<384>(SBUF((j + 3) & 3), qg + (size_t)(j + 3) * 12288, 384, tid);
            const char* bp = SBUF(j & 3) + colB * 384;
            f32x4 acc = f32x4{0,0,0,0};
#pragma unroll
            for (int ks = 0; ks < 6; ++ks)
                acc = MFMA(aT[ks], LD8(bp + ((ks * 64 + slot16) ^ xp)), acc);
            int col = (j % 6) * 32 + colB;
            float bias = qbr[j];
            if (j < 6) {
#pragma unroll
                for (int j2 = 0; j2 < 4; ++j2) qb[(orow + j2) * 200 + col] = f2bf(acc[j2] + bias);
            } else if (j < 12) {
#pragma unroll
                for (int j2 = 0; j2 < 4; ++j2) kb[(orow + j2) * 200 + col] = f2bf(acc[j2] + bias);
            } else {
                ushort4 pk;
                pk.x = f2bf(acc[0] + bias); pk.y = f2bf(acc[1] + bias);
                pk.z = f2bf(acc[2] + bias); pk.w = f2bf(acc[3] + bias);
                *reinterpret_cast<ushort4*>(&vT[col * 72 + orow]) = pk;  // transposed
            }
        }
    }
    LGKM0; SBAR;

    // ================ Ph3: attention ================
    {
        const float scale = 0.14433756729740643f;  // 1/sqrt(48)
        ushort* P2b0 = (ushort*)(LDS + cc * 9216);            // heads 0,1
        ushort* P2b1 = (ushort*)(LDS + 104448 + cc * 9216);   // heads 2,3
#pragma unroll
        for (int p = 0; p < 2; ++p) {
            int h = p * 2 + cc;
            ushort* P2 = p ? P2b1 : P2b0;
            float rb[4][4];
#pragma unroll
            for (int j2 = 0; j2 < 4; ++j2) {
                int qrow = orow + j2, qh = qrow >> 3, qw = qrow & 7;
#pragma unroll
                for (int nf = 0; nf < 4; ++nf) {
                    int krow = l15 + nf * 16;
                    rb[j2][nf] = rpb[((qh - (krow >> 3) + 7) * 15 + (qw - (krow & 7) + 7)) * 4 + h];
                }
            }
            uint4 z = make_uint4(0, 0, 0, 0);
            const char* qrp = (const char*)qb + rowA * 400 + h * 96;
            uint4 qa1 = *(const uint4*)(qrp + slot16);
            uint4 qa2 = (slot < 2) ? *(const uint4*)(qrp + 64 + slot16) : z;
            f32x4 S[4] = {};
#pragma unroll
            for (int nf = 0; nf < 4; ++nf) {
                const char* kp = (const char*)kb + (l15 + nf * 16) * 400 + h * 96;
                uint4 k1 = *(const uint4*)(kp + slot16);
                uint4 k2 = (slot < 2) ? *(const uint4*)(kp + 64 + slot16) : z;
                S[nf] = MFMA(*(bf16x8*)&qa1, *(bf16x8*)&k1, S[nf]);
                S[nf] = MFMA(*(bf16x8*)&qa2, *(bf16x8*)&k2, S[nf]);
            }
#pragma unroll
            for (int j2 = 0; j2 < 4; ++j2) {
                float sv[4]; float mx = -1e30f;
#pragma unroll
                for (int nf = 0; nf < 4; ++nf) { sv[nf] = S[nf][j2] * scale + rb[j2][nf]; mx = fmaxf(mx, sv[nf]); }
#pragma unroll
                for (int m = 1; m < 16; m <<= 1) mx = fmaxf(mx, __shfl_xor(mx, m));
                float sum = 0.f;
#pragma unroll
                for (int nf = 0; nf < 4; ++nf) { sv[nf] = expf(sv[nf] - mx); sum += sv[nf]; }
#pragma unroll
                for (int m = 1; m < 16; m <<= 1) sum += __shfl_xor(sum, m);
                float inv = 1.f / sum;
                int qrow = orow + j2;
#pragma unroll
                for (int nf = 0; nf < 4; ++nf) P2[qrow * 72 + l15 + nf * 16] = f2bf(sv[nf] * inv);
            }
        }
        LGKM0; SBAR;   // all qb/kb reads done before ob (qb region) writes
#pragma unroll
        for (int p = 0; p < 2; ++p) {
            int h = p * 2 + cc;
            ushort* P2 = p ? P2b1 : P2b0;
            f32x4 O[3] = {};
            const char* prow = (const char*)P2 + rowA * 144;
#pragma unroll
            for (int ki = 0; ki < 2; ++ki) {
                bf16x8 pa = LD8(prow + ki * 64 + slot16);
#pragma unroll
                for (int nf = 0; nf < 3; ++nf) {
                    bf16x8 vb = LD8((const char*)vT + (h * 48 + l15 + nf * 16) * 144 + ki * 64 + slot16);
                    O[nf] = MFMA(pa, vb, O[nf]);
                }
            }
#pragma unroll
            for (int nf = 0; nf < 3; ++nf)
#pragma unroll
                for (int j2 = 0; j2 < 4; ++j2)
                    obp[(orow + j2) * 200 + h * 48 + l15 + nf * 16] = f2bf(O[nf][j2]);
        }
        LGKM0; SBAR;   // ob visible; P2b1 reads done -> stage region reusable
    }
    stageW<384>(SBUF(0), pg, 384, tid);
    stageW<384>(SBUF(1), pg + 12288, 384, tid);
    stageW<384>(SBUF(2), pg + 24576, 384, tid);

    // ================ Ph4: proj (6 jobs) ================
    {
        bf16x8 aO[6];
        const char* orw = (const char*)obp + rowA * 400;
#pragma unroll
        for (int ks = 0; ks < 6; ++ks) aO[ks] = LD8(orw + ks * 64 + slot16);
#pragma unroll
        for (int j = 0; j < 6; ++j) {
            if (j < 4) VMB; else VM0;
            SBAR;
            if (j < 3) stageW<384>(SBUF((j + 3) & 3), pg + (size_t)(j + 3) * 12288, 384, tid);
            const char* bp = SBUF(j & 3) + colB * 384;
#pragma unroll
            for (int ks = 0; ks < 6; ++ks)
                pj[j] = MFMA(aO[ks], LD8(bp + ((ks * 64 + slot16) ^ xp)), pj[j]);
        }
    }
    SBAR;
    stageW<384>(SBUF(0), fg, 384, tid);
    stageW<384>(SBUF(1), fg + 12288, 384, tid);
    stageW<384>(SBUF(2), fg + 24576, 384, tid);
    // ---- residual + LN2 ----
    {
        float s[4] = {}, s2[4] = {};
#pragma unroll
        for (int c = 0; c < 6; ++c)
#pragma unroll
            for (int j2 = 0; j2 < 4; ++j2) {
                float v = tok[c][j2] + alpha * (pj[c][j2] + pbr[c]);
                pj[c][j2] = v;
                s[j2] += v; s2[j2] += v * v;
            }
#pragma unroll
        for (int m = 1; m < 16; m <<= 1)
#pragma unroll
            for (int j2 = 0; j2 < 4; ++j2) { s[j2] += __shfl_xor(s[j2], m); s2[j2] += __shfl_xor(s2[j2], m); }
        if (l15 == 0)
#pragma unroll
            for (int j2 = 0; j2 < 4; ++j2) scr2[(orow + j2) * 2 + cc] = make_float2(s[j2], s2[j2]);
        LGKM0; SBAR;
#pragma unroll
        for (int j2 = 0; j2 < 4; ++j2) {
            int row = orow + j2;
            float2 eA = scr2[row * 2], eB = scr2[row * 2 + 1];
            float mean = (eA.x + eB.x) * (1.f / 192.f);
            float inv = rsqrtf((eA.y + eB.y) * (1.f / 192.f) - mean * mean + 1e-5f);
#pragma unroll
            for (int c = 0; c < 6; ++c)
                t2[row * 200 + c * 32 + colB] = f2bf((pj[c][j2] - mean) * inv * l2gr[c] + l2br[c]);
        }
        LGKM0; SBAR;
    }

    // ================ Ph5: ffn1 + GELU (12 jobs) ================
    {
        bf16x8 aT2[6];
        const char* trow = (const char*)t2 + rowA * 400;
#pragma unroll
        for (int ks = 0; ks < 6; ++ks) aT2[ks] = LD8(trow + ks * 64 + slot16);
#pragma unroll
        for (int j = 0; j < 12; ++j) {
            if (j < 10) VMB; else VM0;
            SBAR;
            if (j < 9) stageW<384>(SBUF((j + 3) & 3), fg + (size_t)(j + 3) * 12288, 384, tid);
            const char* bp = SBUF(j & 3) + colB * 384;
            f32x4 acc = f32x4{0,0,0,0};
#pragma unroll
            for (int ks = 0; ks < 6; ++ks)
                acc = MFMA(aT2[ks], LD8(bp + ((ks * 64 + slot16) ^ xp)), acc);
            int col384 = j * 32 + colB;
            ushort* hb = (j < 6) ? h0 : h1;
            int lcol = (j < 6) ? col384 : col384 - 192;
#pragma unroll
            for (int j2 = 0; j2 < 4; ++j2) {
                float v = acc[j2] + f1br[j];
                v = 0.5f * v * (1.f + erff(v * 0.70710678118654752f));
                hb[(orow + j2) * 200 + lcol] = f2bf(v);
            }
        }
    }
    LGKM0; SBAR;
    stageW<384>(SBUF(0), f2g, 768, tid);
    stageW<384>(SBUF(1), f2g + 384, 768, tid);
    stageW<384>(SBUF(2), f2g + 24576, 768, tid);

    // ================ Ph6: ffn2 (12 jobs) ================
    f32x4 f2a[6];
#pragma unroll
    for (int c = 0; c < 6; ++c) f2a[c] = f32x4{0,0,0,0};
    {
        bf16x8 ah[2][6];
        const char* h0r = (const char*)h0 + rowA * 400;
        const char* h1r = (const char*)h1 + rowA * 400;
#pragma unroll
        for (int ks = 0; ks < 6; ++ks) {
            ah[0][ks] = LD8(h0r + ks * 64 + slot16);
            ah[1][ks] = LD8(h1r + ks * 64 + slot16);
        }
#pragma unroll
        for (int j = 0; j < 12; ++j) {
            if (j < 10) VMB; else VM0;
            SBAR;
            if (j < 9) {
                int jn = j + 3;
                stageW<384>(SBUF(jn & 3), f2g + (size_t)(jn >> 1) * 24576 + (jn & 1) * 384, 768, tid);
            }
            const char* bp = SBUF(j & 3) + colB * 384;
            int c = j >> 1, kh = j & 1;
#pragma unroll
            for (int ks = 0; ks < 6; ++ks)
                f2a[c] = MFMA(ah[kh][ks], LD8(bp + ((ks * 64 + slot16) ^ xp)), f2a[c]);
        }
    }
    stageW<384>(SBUF(0), c2g, 384, tid);
    stageW<384>(SBUF(1), c2g + 12288, 384, tid);
    stageW<384>(SBUF(2), c2g + 24576, 384, tid);
#pragma unroll
    for (int c = 0; c < 6; ++c) {
        int col = c * 32 + colB;
#pragma unroll
        for (int j2 = 0; j2 < 4; ++j2)
            o2[(orow + j2) * 200 + col] = f2bf(pj[c][j2] + f2a[c][j2] + f2br[c]);
    }
    LGKM0; SBAR;

    // ================ Ph7: conv2 -> y bf16 (8 jobs) ================
    {
        bf16x8 aO2[6];
        const char* o2r = (const char*)o2 + rowA * 400;
#pragma unroll
        for (int ks = 0; ks < 6; ++ks) aO2[ks] = LD8(o2r + ks * 64 + slot16);
        ushort* yb = y + (size_t)b * 64 * 256;
#pragma unroll
        for (int j = 0; j < 8; ++j) {
            if (j < 6) VMB; else VM0;
            SBAR;
            if (j < 5) stageW<384>(SBUF((j + 3) & 3), c2g + (size_t)(j + 3) * 12288, 384, tid);
            const char* bp = SBUF(j & 3) + colB * 384;
            f32x4 acc = f32x4{0,0,0,0};
#pragma unroll
            for (int ks = 0; ks < 6; ++ks)
                acc = MFMA(aO2[ks], LD8(bp + ((ks * 64 + slot16) ^ xp)), acc);
            int col = j * 32 + colB;
#pragma unroll
            for (int j2 = 0; j2 < 4; ++j2)
                yb[(size_t)(orow + j2) * 256 + col] = f2bf(acc[j2]);
        }
    }
#undef SBUF
}

// ---------------- final: out = x + broadcast(y bf16), non-temporal out stores ----------------
__global__ __launch_bounds__(256) void final_kernel(const float* __restrict__ x,
                                                    const ushort* __restrict__ y,
                                                    float* __restrict__ out) {
    size_t g = (size_t)blockIdx.x * 256 + threadIdx.x;
    int w4 = g & 7, hh = (g >> 3) & 31, c = (g >> 8) & 255, b = (int)(g >> 16);
    int p = (hh >> 2) * 8 + w4;
    u32 yu = y[((size_t)b * NP + p) * Cch + c];
    union { u32 u; float f; } cv; cv.u = yu << 16;
    float yv = cv.f;
    f32x4 xv = *(reinterpret_cast<const f32x4*>(x) + g);
    f32x4 ov = {xv.x + yv, xv.y + yv, xv.z + yv, xv.w + yv};
    __builtin_nontemporal_store(ov, reinterpret_cast<f32x4*>(out) + g);
}

extern "C" void kernel_launch(void* const* d_in, const int* in_sizes, int n_in,
                              void* d_out, int out_size, void* d_ws, size_t ws_size,
                              hipStream_t stream) {
    const float* x       = (const float*)d_in[0];
    const float* conv1_w = (const float*)d_in[1];
    const float* conv2_w = (const float*)d_in[2];
    const float* qkv_w   = (const float*)d_in[3];
    const float* qkv_b   = (const float*)d_in[4];
    const float* proj_w  = (const float*)d_in[5];
    const float* proj_b  = (const float*)d_in[6];
    const float* ffn_w1  = (const float*)d_in[7];
    const float* ffn_b1  = (const float*)d_in[8];
    const float* ffn_w2  = (const float*)d_in[9];
    const float* ffn_b2  = (const float*)d_in[10];
    const float* ln1_g   = (const float*)d_in[11];
    const float* ln1_b   = (const float*)d_in[12];
    const float* ln2_g   = (const float*)d_in[13];
    const float* ln2_b   = (const float*)d_in[14];
    const float* alpha   = (const float*)d_in[15];
    const float* rpb     = (const float*)d_in[16];
    float* out = (float*)d_out;

    ushort* ybuf = (ushort*)d_ws;                 // 8192*256 bf16
    ushort* xm   = ybuf + 2097152;                // 8192*256 bf16
    ushort* wb   = xm + 2097152;                  // 393216 bf16 weights

    prep_kernel<<<2560, 256, 0, stream>>>(x, conv1_w, conv2_w, qkv_w, proj_w, ffn_w1, ffn_w2,
                                          wb, xm);
    token_kernel<<<Bsz, 512, 0, stream>>>(xm, wb, qkv_b, proj_b, ffn_b1, ffn_b2,
                                          ln1_g, ln1_b, ln2_g, ln2_b, alpha, rpb, ybuf);
    final_kernel<<<(Bsz * Cch * Him * Wim) / 1024, 256, 0, stream>>>(x, ybuf, out);
}